// Round 1
// baseline (365.576 us; speedup 1.0000x reference)
//
#include <hip/hip_runtime.h>

#define LEAK 0.2f

static __device__ __forceinline__ float leaky(float e) { return e > 0.f ? e : LEAK * e; }

// ---------------- edge dtype detection (int64 vs int32) ----------------
__global__ void k_detect(const int* __restrict__ ei, int nwords_check, int* __restrict__ flag) {
    if (threadIdx.x == 0 && blockIdx.x == 0) {
        int ok = 1;
        for (int i = 1; i < nwords_check; i += 2)
            if (ei[i] != 0) { ok = 0; break; }
        *flag = ok;  // 1 => int64 layout, 0 => int32 layout
    }
}

// ---------------- CSR build ----------------
__global__ void k_count(const int* __restrict__ ei, const int* __restrict__ flag,
                        int* __restrict__ counts, int E) {
    int e = blockIdx.x * 256 + threadIdx.x;
    if (e >= E) return;
    int is64 = *flag;
    int d = is64 ? ei[(size_t)2 * E + 2 * e] : ei[(size_t)E + e];
    atomicAdd(&counts[d], 1);
}

__global__ void k_scan1(const int* __restrict__ counts, int* __restrict__ incl,
                        int* __restrict__ bsums, int n) {
    __shared__ int s[256];
    int t = threadIdx.x;
    int g = blockIdx.x * 256 + t;
    int v = (g < n) ? counts[g] : 0;
    s[t] = v;
    __syncthreads();
    for (int off = 1; off < 256; off <<= 1) {
        int add = (t >= off) ? s[t - off] : 0;
        __syncthreads();
        s[t] += add;
        __syncthreads();
    }
    if (g < n) incl[g] = s[t];
    if (t == 255) bsums[blockIdx.x] = s[255];
}

__global__ void k_scan2(int* __restrict__ bsums, int nb) {
    __shared__ int s[256];
    int t = threadIdx.x;
    int v = (t < nb) ? bsums[t] : 0;
    s[t] = v;
    __syncthreads();
    for (int off = 1; off < 256; off <<= 1) {
        int add = (t >= off) ? s[t - off] : 0;
        __syncthreads();
        s[t] += add;
        __syncthreads();
    }
    int excl = (t == 0) ? 0 : s[t - 1];
    if (t < nb) bsums[t] = excl;
}

__global__ void k_scan3(const int* __restrict__ incl, const int* __restrict__ bsums,
                        int* __restrict__ rowptr, int n) {
    int g = blockIdx.x * 256 + threadIdx.x;
    if (g < n) rowptr[g + 1] = incl[g] + bsums[blockIdx.x];
    if (g == 0) rowptr[0] = 0;
}

__global__ void k_copy(const int* __restrict__ rowptr, int* __restrict__ fillpos, int n) {
    int g = blockIdx.x * 256 + threadIdx.x;
    if (g < n) fillpos[g] = rowptr[g];
}

__global__ void k_fill(const int* __restrict__ ei, const int* __restrict__ flag,
                       int* __restrict__ fillpos, int* __restrict__ colv, int E) {
    int e = blockIdx.x * 256 + threadIdx.x;
    if (e >= E) return;
    int is64 = *flag;
    int s = is64 ? ei[2 * e] : ei[e];
    int d = is64 ? ei[(size_t)2 * E + 2 * e] : ei[(size_t)E + e];
    int p = atomicAdd(&fillpos[d], 1);
    colv[p] = s;
}

// ---------------- GEMM: H[n][F] = X[n][128] @ W[128][F] ----------------
template <int F>
__global__ __launch_bounds__(256) void k_gemm(const float* __restrict__ X,
                                              const float* __restrict__ W,
                                              float* __restrict__ H, int n) {
    constexpr int K = 128;
    constexpr int CP = F / 2;       // column pairs
    constexpr int RG = 256 / CP;    // row groups per iter (each handles 2 rows)
    constexpr int RPI = 2 * RG;     // rows per iter
    constexpr int ROWS = 16;        // rows per block
    constexpr int ITERS = ROWS / RPI;
    __shared__ float xs[ROWS * K];
    __shared__ float2 ws[K * CP];
    int t = threadIdx.x;
    const float2* Wv = (const float2*)W;
    for (int i = t; i < K * CP; i += 256) ws[i] = Wv[i];
    long long rowbase = (long long)blockIdx.x * ROWS;
    const float4* Xv = (const float4*)X;
    float4* xsv = (float4*)xs;
    long long xbase4 = rowbase * (K / 4);
    long long lim4 = (long long)n * (K / 4);
    for (int i = t; i < ROWS * K / 4; i += 256) {
        long long gi = xbase4 + i;
        xsv[i] = (gi < lim4) ? Xv[gi] : make_float4(0.f, 0.f, 0.f, 0.f);
    }
    __syncthreads();
    int cp = t % CP;
    int rg = t / CP;
    for (int it = 0; it < ITERS; ++it) {
        int r0 = it * RPI + rg * 2;
        int r1 = r0 + 1;
        float a00 = 0.f, a01 = 0.f, a10 = 0.f, a11 = 0.f;
#pragma unroll 8
        for (int k = 0; k < K; ++k) {
            float2 w = ws[k * CP + cp];
            float xa = xs[r0 * K + k];
            float xb = xs[r1 * K + k];
            a00 = fmaf(xa, w.x, a00);
            a01 = fmaf(xa, w.y, a01);
            a10 = fmaf(xb, w.x, a10);
            a11 = fmaf(xb, w.y, a11);
        }
        float2* Hv = (float2*)H;
        long long gr0 = rowbase + r0, gr1 = rowbase + r1;
        if (gr0 < n) Hv[gr0 * CP + cp] = make_float2(a00, a01);
        if (gr1 < n) Hv[gr1 * CP + cp] = make_float2(a10, a11);
    }
}

// ---------------- alpha_s / alpha_d: per-row dot products ----------------
template <int FPL>  // features per lane (F = FPL*64)
__global__ __launch_bounds__(256) void k_alpha(const float* __restrict__ H,
                                               const float* __restrict__ asrc,
                                               const float* __restrict__ adst,
                                               float* __restrict__ out_s,
                                               float* __restrict__ out_d, int n) {
    int node = blockIdx.x * 4 + (threadIdx.x >> 6);
    int lane = threadIdx.x & 63;
    if (node >= n) return;
    float ps, pd;
    if constexpr (FPL == 2) {
        const float2* H2 = (const float2*)H;
        float2 h = H2[(size_t)node * 64 + lane];
        float2 s2 = ((const float2*)asrc)[lane];
        float2 d2 = ((const float2*)adst)[lane];
        ps = h.x * s2.x + h.y * s2.y;
        pd = h.x * d2.x + h.y * d2.y;
    } else {
        float h = H[(size_t)node * 64 + lane];
        ps = h * asrc[lane];
        pd = h * adst[lane];
    }
    for (int off = 32; off; off >>= 1) {
        ps += __shfl_xor(ps, off);
        pd += __shfl_xor(pd, off);
    }
    if (lane == 0) {
        out_s[node] = ps;
        out_d[node] = pd;
    }
}

// ---------------- fused segment softmax + aggregation (wave per dst node) ----------------
template <int FPL, bool RELU>
__global__ __launch_bounds__(256) void k_agg(const int* __restrict__ rowptr,
                                             const int* __restrict__ colv,
                                             const float* __restrict__ as_,
                                             const float* __restrict__ ad_,
                                             const float* __restrict__ H,
                                             const float* __restrict__ bias,
                                             float* __restrict__ OUT, int n) {
    int node = blockIdx.x * 4 + (threadIdx.x >> 6);
    int lane = threadIdx.x & 63;
    if (node >= n) return;
    int rs = rowptr[node], re = rowptr[node + 1];
    float adi = ad_[node];
    float e_self = leaky(as_[node] + adi);
    float m = e_self;
    for (int j = rs + lane; j < re; j += 64) {
        float e = leaky(as_[colv[j]] + adi);
        m = fmaxf(m, e);
    }
    for (int off = 32; off; off >>= 1) m = fmaxf(m, __shfl_xor(m, off));
    float ssum = 0.f;
    for (int j = rs + lane; j < re; j += 64) {
        float e = leaky(as_[colv[j]] + adi);
        ssum += __expf(e - m);
    }
    for (int off = 32; off; off >>= 1) ssum += __shfl_xor(ssum, off);
    ssum += __expf(e_self - m);
    float inv = 1.f / ssum;
    float wself = __expf(e_self - m) * inv;
    if constexpr (FPL == 2) {
        const float2* H2 = (const float2*)H;
        float2 hv = H2[(size_t)node * 64 + lane];
        float ax = wself * hv.x, ay = wself * hv.y;
        for (int j = rs; j < re; ++j) {
            int s = colv[j];
            float w = __expf(leaky(as_[s] + adi) - m) * inv;
            float2 h2 = H2[(size_t)s * 64 + lane];
            ax = fmaf(w, h2.x, ax);
            ay = fmaf(w, h2.y, ay);
        }
        float2 bv = ((const float2*)bias)[lane];
        ax += bv.x;
        ay += bv.y;
        if (RELU) {
            ax = fmaxf(ax, 0.f);
            ay = fmaxf(ay, 0.f);
        }
        ((float2*)OUT)[(size_t)node * 64 + lane] = make_float2(ax, ay);
    } else {
        float acc = wself * H[(size_t)node * 64 + lane];
        for (int j = rs; j < re; ++j) {
            int s = colv[j];
            float w = __expf(leaky(as_[s] + adi) - m) * inv;
            acc = fmaf(w, H[(size_t)s * 64 + lane], acc);
        }
        acc += bias[lane];
        if (RELU) acc = fmaxf(acc, 0.f);
        OUT[(size_t)node * 64 + lane] = acc;
    }
}

// ---------------- host launch ----------------
extern "C" void kernel_launch(void* const* d_in, const int* in_sizes, int n_in,
                              void* d_out, int out_size, void* d_ws, size_t ws_size,
                              hipStream_t stream) {
    const float* x   = (const float*)d_in[0];
    const int*   ei  = (const int*)d_in[1];
    const float* W1  = (const float*)d_in[2];
    const float* a1s = (const float*)d_in[3];
    const float* a1d = (const float*)d_in[4];
    const float* b1  = (const float*)d_in[5];
    const float* W2  = (const float*)d_in[6];
    const float* a2s = (const float*)d_in[7];
    const float* a2d = (const float*)d_in[8];
    const float* b2  = (const float*)d_in[9];
    float* out = (float*)d_out;

    int N = in_sizes[0] / 128;   // 50000
    int E = in_sizes[1] / 2;     // 640000

    // workspace carve-up
    size_t off = 0;
    auto alloc = [&](size_t bytes) -> void* {
        off = (off + 255) & ~(size_t)255;
        void* p = (char*)d_ws + off;
        off += bytes;
        return p;
    };
    float* h      = (float*)alloc((size_t)N * 128 * 4);  // h1, reused as h2
    float* out1   = (float*)alloc((size_t)N * 128 * 4);
    float* as_    = (float*)alloc((size_t)N * 4);
    float* ad_    = (float*)alloc((size_t)N * 4);
    int* counts   = (int*)alloc((size_t)N * 4);
    int* rowptr   = (int*)alloc((size_t)(N + 1) * 4);
    int* fillpos  = (int*)alloc((size_t)N * 4);
    int* incl     = (int*)alloc((size_t)N * 4);
    int* bsums    = (int*)alloc(1024);
    int* colv     = (int*)alloc((size_t)E * 4);
    int* flag     = (int*)alloc(256);

    int blocksE = (E + 255) / 256;
    int NB = (N + 255) / 256;          // <= 256 required for single-block scan2
    int blocksN4 = (N + 3) / 4;
    int blocksG = (N + 15) / 16;

    hipMemsetAsync(counts, 0, (size_t)N * 4, stream);
    int nchk = 2 * E < 512 ? 2 * E : 512;
    k_detect<<<1, 64, 0, stream>>>(ei, nchk, flag);
    k_count<<<blocksE, 256, 0, stream>>>(ei, flag, counts, E);
    k_scan1<<<NB, 256, 0, stream>>>(counts, incl, bsums, N);
    k_scan2<<<1, 256, 0, stream>>>(bsums, NB);
    k_scan3<<<NB, 256, 0, stream>>>(incl, bsums, rowptr, N);
    k_copy<<<NB, 256, 0, stream>>>(rowptr, fillpos, N);
    k_fill<<<blocksE, 256, 0, stream>>>(ei, flag, fillpos, colv, E);

    // layer 1: Fh = 128
    k_gemm<128><<<blocksG, 256, 0, stream>>>(x, W1, h, N);
    k_alpha<2><<<blocksN4, 256, 0, stream>>>(h, a1s, a1d, as_, ad_, N);
    k_agg<2, true><<<blocksN4, 256, 0, stream>>>(rowptr, colv, as_, ad_, h, b1, out1, N);

    // layer 2: Fout = 64 (h2 reuses h buffer)
    k_gemm<64><<<blocksG, 256, 0, stream>>>(out1, W2, h, N);
    k_alpha<1><<<blocksN4, 256, 0, stream>>>(h, a2s, a2d, as_, ad_, N);
    k_agg<1, false><<<blocksN4, 256, 0, stream>>>(rowptr, colv, as_, ad_, h, b2, out, N);
}

// Round 2
// 282.699 us; speedup vs baseline: 1.2932x; 1.2932x over previous
//
#include <hip/hip_runtime.h>

#define LEAK 0.2f

static __device__ __forceinline__ float leaky(float e) { return e > 0.f ? e : LEAK * e; }

// ---------------- edge dtype detection (int64 vs int32) ----------------
__global__ void k_detect(const int* __restrict__ ei, int nwords_check, int* __restrict__ flag) {
    int lane = threadIdx.x;  // 64 lanes
    int bad = 0;
    for (int i = 1 + 2 * lane; i < nwords_check; i += 128) bad |= (ei[i] != 0);
    unsigned long long anybad = __ballot(bad != 0);
    if (lane == 0) *flag = (anybad == 0ULL) ? 1 : 0;  // 1 => int64 layout
}

// ---------------- CSR build ----------------
__global__ void k_count(const int* __restrict__ ei, const int* __restrict__ flag,
                        int* __restrict__ counts, int E) {
    int e = blockIdx.x * 256 + threadIdx.x;
    if (e >= E) return;
    int is64 = *flag;
    int d = is64 ? ei[(size_t)2 * E + 2 * e] : ei[(size_t)E + e];
    atomicAdd(&counts[d], 1);
}

__global__ void k_scan1(const int* __restrict__ counts, int* __restrict__ incl,
                        int* __restrict__ bsums, int n) {
    __shared__ int s[256];
    int t = threadIdx.x;
    int g = blockIdx.x * 256 + t;
    int v = (g < n) ? counts[g] : 0;
    s[t] = v;
    __syncthreads();
    for (int off = 1; off < 256; off <<= 1) {
        int add = (t >= off) ? s[t - off] : 0;
        __syncthreads();
        s[t] += add;
        __syncthreads();
    }
    if (g < n) incl[g] = s[t];
    if (t == 255) bsums[blockIdx.x] = s[255];
}

__global__ void k_scan2(int* __restrict__ bsums, int nb) {
    __shared__ int s[256];
    int t = threadIdx.x;
    int v = (t < nb) ? bsums[t] : 0;
    s[t] = v;
    __syncthreads();
    for (int off = 1; off < 256; off <<= 1) {
        int add = (t >= off) ? s[t - off] : 0;
        __syncthreads();
        s[t] += add;
        __syncthreads();
    }
    int excl = (t == 0) ? 0 : s[t - 1];
    if (t < nb) bsums[t] = excl;
}

// writes rowptr AND fillpos (exclusive prefix) in one pass
__global__ void k_scan3(const int* __restrict__ incl, const int* __restrict__ bsums,
                        const int* __restrict__ counts, int* __restrict__ rowptr,
                        int* __restrict__ fillpos, int n) {
    int g = blockIdx.x * 256 + threadIdx.x;
    if (g < n) {
        int inc = incl[g] + bsums[blockIdx.x];
        rowptr[g + 1] = inc;
        fillpos[g] = inc - counts[g];
    }
    if (g == 0) rowptr[0] = 0;
}

__global__ void k_fill(const int* __restrict__ ei, const int* __restrict__ flag,
                       int* __restrict__ fillpos, int* __restrict__ colv, int E) {
    int e = blockIdx.x * 256 + threadIdx.x;
    if (e >= E) return;
    int is64 = *flag;
    int s = is64 ? ei[2 * e] : ei[e];
    int d = is64 ? ei[(size_t)2 * E + 2 * e] : ei[(size_t)E + e];
    int p = atomicAdd(&fillpos[d], 1);
    colv[p] = s;
}

// ---------------- GEMM: H[n][F] = X[n][128] @ W[128][F] ----------------
template <int F>
__global__ __launch_bounds__(256) void k_gemm(const float* __restrict__ X,
                                              const float* __restrict__ W,
                                              float* __restrict__ H, int n) {
    constexpr int K = 128;
    constexpr int CP = F / 2;       // column pairs
    constexpr int RG = 256 / CP;    // row groups per iter (each handles 2 rows)
    constexpr int RPI = 2 * RG;     // rows per iter
    constexpr int ROWS = 16;        // rows per block
    constexpr int ITERS = ROWS / RPI;
    __shared__ float xs[ROWS * K];
    __shared__ float2 ws[K * CP];
    int t = threadIdx.x;
    const float2* Wv = (const float2*)W;
    for (int i = t; i < K * CP; i += 256) ws[i] = Wv[i];
    long long rowbase = (long long)blockIdx.x * ROWS;
    const float4* Xv = (const float4*)X;
    float4* xsv = (float4*)xs;
    long long xbase4 = rowbase * (K / 4);
    long long lim4 = (long long)n * (K / 4);
    for (int i = t; i < ROWS * K / 4; i += 256) {
        long long gi = xbase4 + i;
        xsv[i] = (gi < lim4) ? Xv[gi] : make_float4(0.f, 0.f, 0.f, 0.f);
    }
    __syncthreads();
    int cp = t % CP;
    int rg = t / CP;
    for (int it = 0; it < ITERS; ++it) {
        int r0 = it * RPI + rg * 2;
        int r1 = r0 + 1;
        float a00 = 0.f, a01 = 0.f, a10 = 0.f, a11 = 0.f;
#pragma unroll 8
        for (int k = 0; k < K; ++k) {
            float2 w = ws[k * CP + cp];
            float xa = xs[r0 * K + k];
            float xb = xs[r1 * K + k];
            a00 = fmaf(xa, w.x, a00);
            a01 = fmaf(xa, w.y, a01);
            a10 = fmaf(xb, w.x, a10);
            a11 = fmaf(xb, w.y, a11);
        }
        float2* Hv = (float2*)H;
        long long gr0 = rowbase + r0, gr1 = rowbase + r1;
        if (gr0 < n) Hv[gr0 * CP + cp] = make_float2(a00, a01);
        if (gr1 < n) Hv[gr1 * CP + cp] = make_float2(a10, a11);
    }
}

// ---------------- alpha_s / alpha_d: per-row dot products ----------------
template <int FPL>  // features per lane (F = FPL*64)
__global__ __launch_bounds__(256) void k_alpha(const float* __restrict__ H,
                                               const float* __restrict__ asrc,
                                               const float* __restrict__ adst,
                                               float* __restrict__ out_s,
                                               float* __restrict__ out_d, int n) {
    int node = blockIdx.x * 4 + (threadIdx.x >> 6);
    int lane = threadIdx.x & 63;
    if (node >= n) return;
    float ps, pd;
    if constexpr (FPL == 2) {
        const float2* H2 = (const float2*)H;
        float2 h = H2[(size_t)node * 64 + lane];
        float2 s2 = ((const float2*)asrc)[lane];
        float2 d2 = ((const float2*)adst)[lane];
        ps = h.x * s2.x + h.y * s2.y;
        pd = h.x * d2.x + h.y * d2.y;
    } else {
        float h = H[(size_t)node * 64 + lane];
        ps = h * asrc[lane];
        pd = h * adst[lane];
    }
    for (int off = 32; off; off >>= 1) {
        ps += __shfl_xor(ps, off);
        pd += __shfl_xor(pd, off);
    }
    if (lane == 0) {
        out_s[node] = ps;
        out_d[node] = pd;
    }
}

// ---------------- fused segment softmax + aggregation (wave per dst node) ----------------
// Lane l holds edge (rs+l)'s src index + softmax weight in registers; the
// gather loop broadcasts them via __shfl (no memory deps) and keeps 4
// independent h-row loads in flight. Inactive lanes hold (src=node, w=0)
// so the loop body runs unconditionally on a count rounded up to 4.
template <int FPL, bool RELU>
__global__ __launch_bounds__(256) void k_agg(const int* __restrict__ rowptr,
                                             const int* __restrict__ colv,
                                             const float* __restrict__ as_,
                                             const float* __restrict__ ad_,
                                             const float* __restrict__ H,
                                             const float* __restrict__ bias,
                                             float* __restrict__ OUT, int n) {
    int node = blockIdx.x * 4 + (threadIdx.x >> 6);
    int lane = threadIdx.x & 63;
    if (node >= n) return;
    int rs = rowptr[node], re = rowptr[node + 1];
    int deg = re - rs;
    float adi = ad_[node];
    float e_self = leaky(as_[node] + adi);

    int scol = node;
    float e_l = -3.0e38f;
    if (lane < deg) {
        scol = colv[rs + lane];
        e_l = leaky(as_[scol] + adi);
    }
    float m = fmaxf(e_l, e_self);
    for (int base = 64; base < deg; base += 64) {  // rare: deg > 64
        if (base + lane < deg) m = fmaxf(m, leaky(as_[colv[rs + base + lane]] + adi));
    }
#pragma unroll
    for (int off = 32; off; off >>= 1) m = fmaxf(m, __shfl_xor(m, off));

    float p_l = (lane < deg) ? __expf(e_l - m) : 0.f;
    float ssum = p_l;
    for (int base = 64; base < deg; base += 64) {
        if (base + lane < deg) ssum += __expf(leaky(as_[colv[rs + base + lane]] + adi) - m);
    }
#pragma unroll
    for (int off = 32; off; off >>= 1) ssum += __shfl_xor(ssum, off);
    float pself = __expf(e_self - m);
    ssum += pself;
    float inv = 1.f / ssum;
    float w_l = p_l * inv;     // this lane's edge weight (first 64 edges)
    float wself = pself * inv;

    int cnt = deg < 64 ? deg : 64;
    int cnt4 = (cnt + 3) & ~3;

    if constexpr (FPL == 2) {
        const float2* __restrict__ H2 = (const float2*)H;
        float2 hv = H2[(size_t)node * 64 + lane];
        float ax = wself * hv.x, ay = wself * hv.y;
        for (int i = 0; i < cnt4; i += 4) {
            int s0 = __shfl(scol, i), s1 = __shfl(scol, i + 1);
            int s2 = __shfl(scol, i + 2), s3 = __shfl(scol, i + 3);
            float w0 = __shfl(w_l, i), w1 = __shfl(w_l, i + 1);
            float w2 = __shfl(w_l, i + 2), w3 = __shfl(w_l, i + 3);
            float2 g0 = H2[(size_t)s0 * 64 + lane];
            float2 g1 = H2[(size_t)s1 * 64 + lane];
            float2 g2 = H2[(size_t)s2 * 64 + lane];
            float2 g3 = H2[(size_t)s3 * 64 + lane];
            ax = fmaf(w0, g0.x, ax); ay = fmaf(w0, g0.y, ay);
            ax = fmaf(w1, g1.x, ax); ay = fmaf(w1, g1.y, ay);
            ax = fmaf(w2, g2.x, ax); ay = fmaf(w2, g2.y, ay);
            ax = fmaf(w3, g3.x, ax); ay = fmaf(w3, g3.y, ay);
        }
        for (int j = rs + 64; j < re; ++j) {  // rare: deg > 64
            int s = colv[j];
            float w = __expf(leaky(as_[s] + adi) - m) * inv;
            float2 g = H2[(size_t)s * 64 + lane];
            ax = fmaf(w, g.x, ax); ay = fmaf(w, g.y, ay);
        }
        float2 bv = ((const float2*)bias)[lane];
        ax += bv.x;
        ay += bv.y;
        if (RELU) {
            ax = fmaxf(ax, 0.f);
            ay = fmaxf(ay, 0.f);
        }
        ((float2*)OUT)[(size_t)node * 64 + lane] = make_float2(ax, ay);
    } else {
        float acc = wself * H[(size_t)node * 64 + lane];
        for (int i = 0; i < cnt4; i += 4) {
            int s0 = __shfl(scol, i), s1 = __shfl(scol, i + 1);
            int s2 = __shfl(scol, i + 2), s3 = __shfl(scol, i + 3);
            float w0 = __shfl(w_l, i), w1 = __shfl(w_l, i + 1);
            float w2 = __shfl(w_l, i + 2), w3 = __shfl(w_l, i + 3);
            float g0 = H[(size_t)s0 * 64 + lane];
            float g1 = H[(size_t)s1 * 64 + lane];
            float g2 = H[(size_t)s2 * 64 + lane];
            float g3 = H[(size_t)s3 * 64 + lane];
            acc = fmaf(w0, g0, acc);
            acc = fmaf(w1, g1, acc);
            acc = fmaf(w2, g2, acc);
            acc = fmaf(w3, g3, acc);
        }
        for (int j = rs + 64; j < re; ++j) {
            int s = colv[j];
            float w = __expf(leaky(as_[s] + adi) - m) * inv;
            acc = fmaf(w, H[(size_t)s * 64 + lane], acc);
        }
        acc += bias[lane];
        if (RELU) acc = fmaxf(acc, 0.f);
        OUT[(size_t)node * 64 + lane] = acc;
    }
}

// ---------------- host launch ----------------
extern "C" void kernel_launch(void* const* d_in, const int* in_sizes, int n_in,
                              void* d_out, int out_size, void* d_ws, size_t ws_size,
                              hipStream_t stream) {
    const float* x   = (const float*)d_in[0];
    const int*   ei  = (const int*)d_in[1];
    const float* W1  = (const float*)d_in[2];
    const float* a1s = (const float*)d_in[3];
    const float* a1d = (const float*)d_in[4];
    const float* b1  = (const float*)d_in[5];
    const float* W2  = (const float*)d_in[6];
    const float* a2s = (const float*)d_in[7];
    const float* a2d = (const float*)d_in[8];
    const float* b2  = (const float*)d_in[9];
    float* out = (float*)d_out;

    int N = in_sizes[0] / 128;   // 50000
    int E = in_sizes[1] / 2;     // 640000

    // workspace carve-up
    size_t off = 0;
    auto alloc = [&](size_t bytes) -> void* {
        off = (off + 255) & ~(size_t)255;
        void* p = (char*)d_ws + off;
        off += bytes;
        return p;
    };
    float* h      = (float*)alloc((size_t)N * 128 * 4);  // h1, reused as h2
    float* out1   = (float*)alloc((size_t)N * 128 * 4);
    float* as_    = (float*)alloc((size_t)N * 4);
    float* ad_    = (float*)alloc((size_t)N * 4);
    int* counts   = (int*)alloc((size_t)N * 4);
    int* rowptr   = (int*)alloc((size_t)(N + 1) * 4);
    int* fillpos  = (int*)alloc((size_t)N * 4);
    int* incl     = (int*)alloc((size_t)N * 4);
    int* bsums    = (int*)alloc(1024);
    int* colv     = (int*)alloc((size_t)E * 4);
    int* flag     = (int*)alloc(256);

    int blocksE = (E + 255) / 256;
    int NB = (N + 255) / 256;          // <= 256 required for single-block scan2
    int blocksN4 = (N + 3) / 4;
    int blocksG = (N + 15) / 16;

    hipMemsetAsync(counts, 0, (size_t)N * 4, stream);
    int nchk = 2 * E < 512 ? 2 * E : 512;
    k_detect<<<1, 64, 0, stream>>>(ei, nchk, flag);
    k_count<<<blocksE, 256, 0, stream>>>(ei, flag, counts, E);
    k_scan1<<<NB, 256, 0, stream>>>(counts, incl, bsums, N);
    k_scan2<<<1, 256, 0, stream>>>(bsums, NB);
    k_scan3<<<NB, 256, 0, stream>>>(incl, bsums, counts, rowptr, fillpos, N);
    k_fill<<<blocksE, 256, 0, stream>>>(ei, flag, fillpos, colv, E);

    // layer 1: Fh = 128
    k_gemm<128><<<blocksG, 256, 0, stream>>>(x, W1, h, N);
    k_alpha<2><<<blocksN4, 256, 0, stream>>>(h, a1s, a1d, as_, ad_, N);
    k_agg<2, true><<<blocksN4, 256, 0, stream>>>(rowptr, colv, as_, ad_, h, b1, out1, N);

    // layer 2: Fout = 64 (h2 reuses h buffer)
    k_gemm<64><<<blocksG, 256, 0, stream>>>(out1, W2, h, N);
    k_alpha<1><<<blocksN4, 256, 0, stream>>>(h, a2s, a2d, as_, ad_, N);
    k_agg<1, false><<<blocksN4, 256, 0, stream>>>(rowptr, colv, as_, ad_, h, b2, out, N);
}

// Round 3
// 233.111 us; speedup vs baseline: 1.5682x; 1.2127x over previous
//
#include <hip/hip_runtime.h>

#define LEAK 0.2f

static __device__ __forceinline__ float leaky(float e) { return e > 0.f ? e : LEAK * e; }

// ---------------- edge dtype detection (int64 vs int32) ----------------
__global__ void k_detect(const int* __restrict__ ei, int nwords_check, int* __restrict__ flag) {
    int lane = threadIdx.x;  // 64 lanes
    int bad = 0;
    for (int i = 1 + 2 * lane; i < nwords_check; i += 128) bad |= (ei[i] != 0);
    unsigned long long anybad = __ballot(bad != 0);
    if (lane == 0) *flag = (anybad == 0ULL) ? 1 : 0;  // 1 => int64 layout
}

// ---------------- CSR build ----------------
__global__ void k_count(const int* __restrict__ ei, const int* __restrict__ flag,
                        int* __restrict__ counts, int E) {
    int e = blockIdx.x * 256 + threadIdx.x;
    if (e >= E) return;
    int is64 = *flag;
    int d = is64 ? ei[(size_t)2 * E + 2 * e] : ei[(size_t)E + e];
    atomicAdd(&counts[d], 1);
}

__global__ void k_scan1(const int* __restrict__ counts, int* __restrict__ incl,
                        int* __restrict__ bsums, int n) {
    __shared__ int s[256];
    int t = threadIdx.x;
    int g = blockIdx.x * 256 + t;
    int v = (g < n) ? counts[g] : 0;
    s[t] = v;
    __syncthreads();
    for (int off = 1; off < 256; off <<= 1) {
        int add = (t >= off) ? s[t - off] : 0;
        __syncthreads();
        s[t] += add;
        __syncthreads();
    }
    if (g < n) incl[g] = s[t];
    if (t == 255) bsums[blockIdx.x] = s[255];
}

__global__ void k_scan2(int* __restrict__ bsums, int nb) {
    __shared__ int s[256];
    int t = threadIdx.x;
    int v = (t < nb) ? bsums[t] : 0;
    s[t] = v;
    __syncthreads();
    for (int off = 1; off < 256; off <<= 1) {
        int add = (t >= off) ? s[t - off] : 0;
        __syncthreads();
        s[t] += add;
        __syncthreads();
    }
    int excl = (t == 0) ? 0 : s[t - 1];
    if (t < nb) bsums[t] = excl;
}

// writes rowptr AND fillpos (exclusive prefix) in one pass
__global__ void k_scan3(const int* __restrict__ incl, const int* __restrict__ bsums,
                        const int* __restrict__ counts, int* __restrict__ rowptr,
                        int* __restrict__ fillpos, int n) {
    int g = blockIdx.x * 256 + threadIdx.x;
    if (g < n) {
        int inc = incl[g] + bsums[blockIdx.x];
        rowptr[g + 1] = inc;
        fillpos[g] = inc - counts[g];
    }
    if (g == 0) rowptr[0] = 0;
}

__global__ void k_fill(const int* __restrict__ ei, const int* __restrict__ flag,
                       int* __restrict__ fillpos, int* __restrict__ colv, int E) {
    int e = blockIdx.x * 256 + threadIdx.x;
    if (e >= E) return;
    int is64 = *flag;
    int s = is64 ? ei[2 * e] : ei[e];
    int d = is64 ? ei[(size_t)2 * E + 2 * e] : ei[(size_t)E + e];
    int p = atomicAdd(&fillpos[d], 1);
    colv[p] = s;
}

// ---------------- GEMM: H[n][F] = X[n][128] @ W[128][F] ----------------
// 64x64 output tile per block, 256 threads, 4x4 register tile per thread.
// k processed in chunks of 4 so both fragments are ds_read_b128:
//   8 b128 LDS reads per 64 FMAs -> FMA-bound.
// Xs padded to 132 floats/row (16B-aligned, reads <=2-way bank alias = free).
template <int F>
__global__ __launch_bounds__(256) void k_gemm(const float* __restrict__ X,
                                              const float* __restrict__ W,
                                              float* __restrict__ H, int n) {
    constexpr int K = 128;
    constexpr int BM = 64, BN = 64;
    constexpr int XPAD = 132;
    __shared__ float xs[BM * XPAD];   // 33792 B
    __shared__ float ws[K * BN];      // 32768 B
    int t = threadIdx.x;
    constexpr int NB = F / BN;        // col-tiles
    int bm = blockIdx.x / NB;
    int bn = blockIdx.x % NB;
    long long row0 = (long long)bm * BM;

    // stage W tile [128][64]
    const float4* W4 = (const float4*)W;
    float4* ws4 = (float4*)ws;
#pragma unroll
    for (int i = t; i < K * (BN / 4); i += 256) {
        int k = i / (BN / 4), c4 = i % (BN / 4);
        ws4[k * (BN / 4) + c4] = W4[(size_t)k * (F / 4) + bn * (BN / 4) + c4];
    }
    // stage X tile [64][132] (padded row-major)
    const float4* X4 = (const float4*)X;
#pragma unroll
    for (int i = t; i < BM * (K / 4); i += 256) {
        int r = i / (K / 4), c4 = i % (K / 4);
        long long gr = row0 + r;
        float4 v = make_float4(0.f, 0.f, 0.f, 0.f);
        if (gr < n) v = X4[gr * (K / 4) + c4];
        *(float4*)&xs[r * XPAD + 4 * c4] = v;
    }
    __syncthreads();

    int tx = t & 15;   // col group (x4)
    int ty = t >> 4;   // row group (x4)

    float acc[4][4] = {};
    for (int kb = 0; kb < K; kb += 4) {
        float4 a[4], b[4];
#pragma unroll
        for (int i = 0; i < 4; ++i)
            a[i] = *(const float4*)&xs[(ty * 4 + i) * XPAD + kb];
#pragma unroll
        for (int j = 0; j < 4; ++j)
            b[j] = *(const float4*)&ws[(kb + j) * BN + tx * 4];
#pragma unroll
        for (int i = 0; i < 4; ++i) {
            acc[i][0] = fmaf(a[i].x, b[0].x, acc[i][0]);
            acc[i][1] = fmaf(a[i].x, b[0].y, acc[i][1]);
            acc[i][2] = fmaf(a[i].x, b[0].z, acc[i][2]);
            acc[i][3] = fmaf(a[i].x, b[0].w, acc[i][3]);
            acc[i][0] = fmaf(a[i].y, b[1].x, acc[i][0]);
            acc[i][1] = fmaf(a[i].y, b[1].y, acc[i][1]);
            acc[i][2] = fmaf(a[i].y, b[1].z, acc[i][2]);
            acc[i][3] = fmaf(a[i].y, b[1].w, acc[i][3]);
            acc[i][0] = fmaf(a[i].z, b[2].x, acc[i][0]);
            acc[i][1] = fmaf(a[i].z, b[2].y, acc[i][1]);
            acc[i][2] = fmaf(a[i].z, b[2].z, acc[i][2]);
            acc[i][3] = fmaf(a[i].z, b[2].w, acc[i][3]);
            acc[i][0] = fmaf(a[i].w, b[3].x, acc[i][0]);
            acc[i][1] = fmaf(a[i].w, b[3].y, acc[i][1]);
            acc[i][2] = fmaf(a[i].w, b[3].z, acc[i][2]);
            acc[i][3] = fmaf(a[i].w, b[3].w, acc[i][3]);
        }
    }

    long long colbase = (long long)bn * BN + tx * 4;
#pragma unroll
    for (int i = 0; i < 4; ++i) {
        long long gr = row0 + ty * 4 + i;
        if (gr < n)
            *(float4*)&H[gr * F + colbase] =
                make_float4(acc[i][0], acc[i][1], acc[i][2], acc[i][3]);
    }
}

// ---------------- alpha_s / alpha_d: per-row dot products ----------------
template <int FPL>  // features per lane (F = FPL*64)
__global__ __launch_bounds__(256) void k_alpha(const float* __restrict__ H,
                                               const float* __restrict__ asrc,
                                               const float* __restrict__ adst,
                                               float* __restrict__ out_s,
                                               float* __restrict__ out_d, int n) {
    int node = blockIdx.x * 4 + (threadIdx.x >> 6);
    int lane = threadIdx.x & 63;
    if (node >= n) return;
    float ps, pd;
    if constexpr (FPL == 2) {
        const float2* H2 = (const float2*)H;
        float2 h = H2[(size_t)node * 64 + lane];
        float2 s2 = ((const float2*)asrc)[lane];
        float2 d2 = ((const float2*)adst)[lane];
        ps = h.x * s2.x + h.y * s2.y;
        pd = h.x * d2.x + h.y * d2.y;
    } else {
        float h = H[(size_t)node * 64 + lane];
        ps = h * asrc[lane];
        pd = h * adst[lane];
    }
    for (int off = 32; off; off >>= 1) {
        ps += __shfl_xor(ps, off);
        pd += __shfl_xor(pd, off);
    }
    if (lane == 0) {
        out_s[node] = ps;
        out_d[node] = pd;
    }
}

// ---------------- fused segment softmax + aggregation (wave per dst node) ----------------
template <int FPL, bool RELU>
__global__ __launch_bounds__(256) void k_agg(const int* __restrict__ rowptr,
                                             const int* __restrict__ colv,
                                             const float* __restrict__ as_,
                                             const float* __restrict__ ad_,
                                             const float* __restrict__ H,
                                             const float* __restrict__ bias,
                                             float* __restrict__ OUT, int n) {
    int node = blockIdx.x * 4 + (threadIdx.x >> 6);
    int lane = threadIdx.x & 63;
    if (node >= n) return;
    int rs = rowptr[node], re = rowptr[node + 1];
    int deg = re - rs;
    float adi = ad_[node];
    float e_self = leaky(as_[node] + adi);

    int scol = node;
    float e_l = -3.0e38f;
    if (lane < deg) {
        scol = colv[rs + lane];
        e_l = leaky(as_[scol] + adi);
    }
    float m = fmaxf(e_l, e_self);
    for (int base = 64; base < deg; base += 64) {  // rare: deg > 64
        if (base + lane < deg) m = fmaxf(m, leaky(as_[colv[rs + base + lane]] + adi));
    }
#pragma unroll
    for (int off = 32; off; off >>= 1) m = fmaxf(m, __shfl_xor(m, off));

    float p_l = (lane < deg) ? __expf(e_l - m) : 0.f;
    float ssum = p_l;
    for (int base = 64; base < deg; base += 64) {
        if (base + lane < deg) ssum += __expf(leaky(as_[colv[rs + base + lane]] + adi) - m);
    }
#pragma unroll
    for (int off = 32; off; off >>= 1) ssum += __shfl_xor(ssum, off);
    float pself = __expf(e_self - m);
    ssum += pself;
    float inv = 1.f / ssum;
    float w_l = p_l * inv;     // this lane's edge weight (first 64 edges)
    float wself = pself * inv;

    int cnt = deg < 64 ? deg : 64;
    int cnt4 = (cnt + 3) & ~3;

    if constexpr (FPL == 2) {
        const float2* __restrict__ H2 = (const float2*)H;
        float2 hv = H2[(size_t)node * 64 + lane];
        float ax = wself * hv.x, ay = wself * hv.y;
        for (int i = 0; i < cnt4; i += 4) {
            int s0 = __shfl(scol, i), s1 = __shfl(scol, i + 1);
            int s2 = __shfl(scol, i + 2), s3 = __shfl(scol, i + 3);
            float w0 = __shfl(w_l, i), w1 = __shfl(w_l, i + 1);
            float w2 = __shfl(w_l, i + 2), w3 = __shfl(w_l, i + 3);
            float2 g0 = H2[(size_t)s0 * 64 + lane];
            float2 g1 = H2[(size_t)s1 * 64 + lane];
            float2 g2 = H2[(size_t)s2 * 64 + lane];
            float2 g3 = H2[(size_t)s3 * 64 + lane];
            ax = fmaf(w0, g0.x, ax); ay = fmaf(w0, g0.y, ay);
            ax = fmaf(w1, g1.x, ax); ay = fmaf(w1, g1.y, ay);
            ax = fmaf(w2, g2.x, ax); ay = fmaf(w2, g2.y, ay);
            ax = fmaf(w3, g3.x, ax); ay = fmaf(w3, g3.y, ay);
        }
        for (int j = rs + 64; j < re; ++j) {  // rare: deg > 64
            int s = colv[j];
            float w = __expf(leaky(as_[s] + adi) - m) * inv;
            float2 g = H2[(size_t)s * 64 + lane];
            ax = fmaf(w, g.x, ax); ay = fmaf(w, g.y, ay);
        }
        float2 bv = ((const float2*)bias)[lane];
        ax += bv.x;
        ay += bv.y;
        if (RELU) {
            ax = fmaxf(ax, 0.f);
            ay = fmaxf(ay, 0.f);
        }
        ((float2*)OUT)[(size_t)node * 64 + lane] = make_float2(ax, ay);
    } else {
        float acc = wself * H[(size_t)node * 64 + lane];
        for (int i = 0; i < cnt4; i += 4) {
            int s0 = __shfl(scol, i), s1 = __shfl(scol, i + 1);
            int s2 = __shfl(scol, i + 2), s3 = __shfl(scol, i + 3);
            float w0 = __shfl(w_l, i), w1 = __shfl(w_l, i + 1);
            float w2 = __shfl(w_l, i + 2), w3 = __shfl(w_l, i + 3);
            float g0 = H[(size_t)s0 * 64 + lane];
            float g1 = H[(size_t)s1 * 64 + lane];
            float g2 = H[(size_t)s2 * 64 + lane];
            float g3 = H[(size_t)s3 * 64 + lane];
            acc = fmaf(w0, g0, acc);
            acc = fmaf(w1, g1, acc);
            acc = fmaf(w2, g2, acc);
            acc = fmaf(w3, g3, acc);
        }
        for (int j = rs + 64; j < re; ++j) {
            int s = colv[j];
            float w = __expf(leaky(as_[s] + adi) - m) * inv;
            acc = fmaf(w, H[(size_t)s * 64 + lane], acc);
        }
        acc += bias[lane];
        if (RELU) acc = fmaxf(acc, 0.f);
        OUT[(size_t)node * 64 + lane] = acc;
    }
}

// ---------------- host launch ----------------
extern "C" void kernel_launch(void* const* d_in, const int* in_sizes, int n_in,
                              void* d_out, int out_size, void* d_ws, size_t ws_size,
                              hipStream_t stream) {
    const float* x   = (const float*)d_in[0];
    const int*   ei  = (const int*)d_in[1];
    const float* W1  = (const float*)d_in[2];
    const float* a1s = (const float*)d_in[3];
    const float* a1d = (const float*)d_in[4];
    const float* b1  = (const float*)d_in[5];
    const float* W2  = (const float*)d_in[6];
    const float* a2s = (const float*)d_in[7];
    const float* a2d = (const float*)d_in[8];
    const float* b2  = (const float*)d_in[9];
    float* out = (float*)d_out;

    int N = in_sizes[0] / 128;   // 50000
    int E = in_sizes[1] / 2;     // 640000

    // workspace carve-up
    size_t off = 0;
    auto alloc = [&](size_t bytes) -> void* {
        off = (off + 255) & ~(size_t)255;
        void* p = (char*)d_ws + off;
        off += bytes;
        return p;
    };
    float* h      = (float*)alloc((size_t)N * 128 * 4);  // h1, reused as h2
    float* out1   = (float*)alloc((size_t)N * 128 * 4);
    float* as_    = (float*)alloc((size_t)N * 4);
    float* ad_    = (float*)alloc((size_t)N * 4);
    int* counts   = (int*)alloc((size_t)N * 4);
    int* rowptr   = (int*)alloc((size_t)(N + 1) * 4);
    int* fillpos  = (int*)alloc((size_t)N * 4);
    int* incl     = (int*)alloc((size_t)N * 4);
    int* bsums    = (int*)alloc(1024);
    int* colv     = (int*)alloc((size_t)E * 4);
    int* flag     = (int*)alloc(256);

    int blocksE = (E + 255) / 256;
    int NB = (N + 255) / 256;          // <= 256 required for single-block scan2
    int blocksN4 = (N + 3) / 4;
    int rowTiles = (N + 63) / 64;

    hipMemsetAsync(counts, 0, (size_t)N * 4, stream);
    int nchk = 2 * E < 512 ? 2 * E : 512;
    k_detect<<<1, 64, 0, stream>>>(ei, nchk, flag);
    k_count<<<blocksE, 256, 0, stream>>>(ei, flag, counts, E);
    k_scan1<<<NB, 256, 0, stream>>>(counts, incl, bsums, N);
    k_scan2<<<1, 256, 0, stream>>>(bsums, NB);
    k_scan3<<<NB, 256, 0, stream>>>(incl, bsums, counts, rowptr, fillpos, N);
    k_fill<<<blocksE, 256, 0, stream>>>(ei, flag, fillpos, colv, E);

    // layer 1: Fh = 128
    k_gemm<128><<<rowTiles * 2, 256, 0, stream>>>(x, W1, h, N);
    k_alpha<2><<<blocksN4, 256, 0, stream>>>(h, a1s, a1d, as_, ad_, N);
    k_agg<2, true><<<blocksN4, 256, 0, stream>>>(rowptr, colv, as_, ad_, h, b1, out1, N);

    // layer 2: Fout = 64 (h2 reuses h buffer)
    k_gemm<64><<<rowTiles, 256, 0, stream>>>(out1, W2, h, N);
    k_alpha<1><<<blocksN4, 256, 0, stream>>>(h, a2s, a2d, as_, ad_, N);
    k_agg<1, false><<<blocksN4, 256, 0, stream>>>(rowptr, colv, as_, ad_, h, b2, out, N);
}

// Round 5
// 231.060 us; speedup vs baseline: 1.5822x; 1.0089x over previous
//
#include <hip/hip_runtime.h>

#define LEAK 0.2f

static __device__ __forceinline__ float leaky(float e) { return e > 0.f ? e : LEAK * e; }

// ---------------- edge dtype detection (int64 vs int32) ----------------
__global__ void k_detect(const int* __restrict__ ei, int nwords_check, int* __restrict__ flag) {
    int lane = threadIdx.x;  // 64 lanes
    int bad = 0;
    for (int i = 1 + 2 * lane; i < nwords_check; i += 128) bad |= (ei[i] != 0);
    unsigned long long anybad = __ballot(bad != 0);
    if (lane == 0) *flag = (anybad == 0ULL) ? 1 : 0;  // 1 => int64 layout
}

// ---------------- CSR build ----------------
__global__ void k_count(const int* __restrict__ ei, const int* __restrict__ flag,
                        int* __restrict__ counts, int E) {
    int e = blockIdx.x * 256 + threadIdx.x;
    if (e >= E) return;
    int is64 = *flag;
    int d = is64 ? ei[(size_t)2 * E + 2 * e] : ei[(size_t)E + e];
    atomicAdd(&counts[d], 1);
}

__global__ void k_scan1(const int* __restrict__ counts, int* __restrict__ incl,
                        int* __restrict__ bsums, int n) {
    __shared__ int s[256];
    int t = threadIdx.x;
    int g = blockIdx.x * 256 + t;
    int v = (g < n) ? counts[g] : 0;
    s[t] = v;
    __syncthreads();
    for (int off = 1; off < 256; off <<= 1) {
        int add = (t >= off) ? s[t - off] : 0;
        __syncthreads();
        s[t] += add;
        __syncthreads();
    }
    if (g < n) incl[g] = s[t];
    if (t == 255) bsums[blockIdx.x] = s[255];
}

__global__ void k_scan2(int* __restrict__ bsums, int nb) {
    __shared__ int s[256];
    int t = threadIdx.x;
    int v = (t < nb) ? bsums[t] : 0;
    s[t] = v;
    __syncthreads();
    for (int off = 1; off < 256; off <<= 1) {
        int add = (t >= off) ? s[t - off] : 0;
        __syncthreads();
        s[t] += add;
        __syncthreads();
    }
    int excl = (t == 0) ? 0 : s[t - 1];
    if (t < nb) bsums[t] = excl;
}

// writes rowptr AND fillpos (exclusive prefix) in one pass
__global__ void k_scan3(const int* __restrict__ incl, const int* __restrict__ bsums,
                        const int* __restrict__ counts, int* __restrict__ rowptr,
                        int* __restrict__ fillpos, int n) {
    int g = blockIdx.x * 256 + threadIdx.x;
    if (g < n) {
        int inc = incl[g] + bsums[blockIdx.x];
        rowptr[g + 1] = inc;
        fillpos[g] = inc - counts[g];
    }
    if (g == 0) rowptr[0] = 0;
}

__global__ void k_fill(const int* __restrict__ ei, const int* __restrict__ flag,
                       int* __restrict__ fillpos, int* __restrict__ colv, int E) {
    int e = blockIdx.x * 256 + threadIdx.x;
    if (e >= E) return;
    int is64 = *flag;
    int s = is64 ? ei[2 * e] : ei[e];
    int d = is64 ? ei[(size_t)2 * E + 2 * e] : ei[(size_t)E + e];
    int p = atomicAdd(&fillpos[d], 1);
    colv[p] = s;
}

// ---------------- GEMM: H[n][F] = X[n][128] @ W[128][F] ----------------
template <int F>
__global__ __launch_bounds__(256) void k_gemm(const float* __restrict__ X,
                                              const float* __restrict__ W,
                                              float* __restrict__ H, int n) {
    constexpr int K = 128;
    constexpr int BM = 64, BN = 64;
    constexpr int XPAD = 132;
    __shared__ float xs[BM * XPAD];   // 33792 B
    __shared__ float ws[K * BN];      // 32768 B
    int t = threadIdx.x;
    constexpr int NB = F / BN;        // col-tiles
    int bm = blockIdx.x / NB;
    int bn = blockIdx.x % NB;
    long long row0 = (long long)bm * BM;

    // stage W tile [128][64]
    const float4* W4 = (const float4*)W;
    float4* ws4 = (float4*)ws;
#pragma unroll
    for (int i = t; i < K * (BN / 4); i += 256) {
        int k = i / (BN / 4), c4 = i % (BN / 4);
        ws4[k * (BN / 4) + c4] = W4[(size_t)k * (F / 4) + bn * (BN / 4) + c4];
    }
    // stage X tile [64][132] (padded row-major)
    const float4* X4 = (const float4*)X;
#pragma unroll
    for (int i = t; i < BM * (K / 4); i += 256) {
        int r = i / (K / 4), c4 = i % (K / 4);
        long long gr = row0 + r;
        float4 v = make_float4(0.f, 0.f, 0.f, 0.f);
        if (gr < n) v = X4[gr * (K / 4) + c4];
        *(float4*)&xs[r * XPAD + 4 * c4] = v;
    }
    __syncthreads();

    int tx = t & 15;   // col group (x4)
    int ty = t >> 4;   // row group (x4)

    float acc[4][4] = {};
    for (int kb = 0; kb < K; kb += 4) {
        float4 a[4], b[4];
#pragma unroll
        for (int i = 0; i < 4; ++i)
            a[i] = *(const float4*)&xs[(ty * 4 + i) * XPAD + kb];
#pragma unroll
        for (int j = 0; j < 4; ++j)
            b[j] = *(const float4*)&ws[(kb + j) * BN + tx * 4];
#pragma unroll
        for (int i = 0; i < 4; ++i) {
            acc[i][0] = fmaf(a[i].x, b[0].x, acc[i][0]);
            acc[i][1] = fmaf(a[i].x, b[0].y, acc[i][1]);
            acc[i][2] = fmaf(a[i].x, b[0].z, acc[i][2]);
            acc[i][3] = fmaf(a[i].x, b[0].w, acc[i][3]);
            acc[i][0] = fmaf(a[i].y, b[1].x, acc[i][0]);
            acc[i][1] = fmaf(a[i].y, b[1].y, acc[i][1]);
            acc[i][2] = fmaf(a[i].y, b[1].z, acc[i][2]);
            acc[i][3] = fmaf(a[i].y, b[1].w, acc[i][3]);
            acc[i][0] = fmaf(a[i].z, b[2].x, acc[i][0]);
            acc[i][1] = fmaf(a[i].z, b[2].y, acc[i][1]);
            acc[i][2] = fmaf(a[i].z, b[2].z, acc[i][2]);
            acc[i][3] = fmaf(a[i].z, b[2].w, acc[i][3]);
            acc[i][0] = fmaf(a[i].w, b[3].x, acc[i][0]);
            acc[i][1] = fmaf(a[i].w, b[3].y, acc[i][1]);
            acc[i][2] = fmaf(a[i].w, b[3].z, acc[i][2]);
            acc[i][3] = fmaf(a[i].w, b[3].w, acc[i][3]);
        }
    }

    long long colbase = (long long)bn * BN + tx * 4;
#pragma unroll
    for (int i = 0; i < 4; ++i) {
        long long gr = row0 + ty * 4 + i;
        if (gr < n)
            *(float4*)&H[gr * F + colbase] =
                make_float4(acc[i][0], acc[i][1], acc[i][2], acc[i][3]);
    }
}

// ---------------- alpha_s / alpha_d: per-row dot products ----------------
template <int FPL>  // features per lane (F = FPL*64)
__global__ __launch_bounds__(256) void k_alpha(const float* __restrict__ H,
                                               const float* __restrict__ asrc,
                                               const float* __restrict__ adst,
                                               float* __restrict__ out_s,
                                               float* __restrict__ out_d, int n) {
    int node = blockIdx.x * 4 + (threadIdx.x >> 6);
    int lane = threadIdx.x & 63;
    if (node >= n) return;
    float ps, pd;
    if constexpr (FPL == 2) {
        const float2* H2 = (const float2*)H;
        float2 h = H2[(size_t)node * 64 + lane];
        float2 s2 = ((const float2*)asrc)[lane];
        float2 d2 = ((const float2*)adst)[lane];
        ps = h.x * s2.x + h.y * s2.y;
        pd = h.x * d2.x + h.y * d2.y;
    } else {
        float h = H[(size_t)node * 64 + lane];
        ps = h * asrc[lane];
        pd = h * adst[lane];
    }
    for (int off = 32; off; off >>= 1) {
        ps += __shfl_xor(ps, off);
        pd += __shfl_xor(pd, off);
    }
    if (lane == 0) {
        out_s[node] = ps;
        out_d[node] = pd;
    }
}

// ---------------- fused segment softmax + aggregation (wave per dst node) ----------------
// Softmax phase: lane l holds edge (rs+l)'s src + weight in registers.
// Gather phase: float4 loads; wave is split into GRP = 64/FG edge-groups so
// one load instruction covers GRP edges (GRP=2 for F=128, GRP=4 for F=64).
// Partial accumulators per group are combined with shfl_xor at the end
// (commutative adds -> deterministic).
template <int F, bool RELU>
__global__ __launch_bounds__(256) void k_agg(const int* __restrict__ rowptr,
                                             const int* __restrict__ colv,
                                             const float* __restrict__ as_,
                                             const float* __restrict__ ad_,
                                             const float* __restrict__ H,
                                             const float* __restrict__ bias,
                                             float* __restrict__ OUT, int n) {
    constexpr int FG = F / 4;        // float4 slots per row (32 or 16)
    constexpr int GRP = 64 / FG;     // edge-groups per wave (2 or 4)  [was 128/F: BUG]
    int node = blockIdx.x * 4 + (threadIdx.x >> 6);
    int lane = threadIdx.x & 63;
    if (node >= n) return;
    int rs = rowptr[node], re = rowptr[node + 1];
    int deg = re - rs;
    float adi = ad_[node];
    float e_self = leaky(as_[node] + adi);

    int scol = node;
    float e_l = -3.0e38f;
    if (lane < deg) {
        scol = colv[rs + lane];
        e_l = leaky(as_[scol] + adi);
    }
    float m = fmaxf(e_l, e_self);
    for (int base = 64; base < deg; base += 64) {  // rare: deg > 64
        if (base + lane < deg) m = fmaxf(m, leaky(as_[colv[rs + base + lane]] + adi));
    }
#pragma unroll
    for (int off = 32; off; off >>= 1) m = fmaxf(m, __shfl_xor(m, off));

    float p_l = (lane < deg) ? __expf(e_l - m) : 0.f;
    float ssum = p_l;
    for (int base = 64; base < deg; base += 64) {
        if (base + lane < deg) ssum += __expf(leaky(as_[colv[rs + base + lane]] + adi) - m);
    }
#pragma unroll
    for (int off = 32; off; off >>= 1) ssum += __shfl_xor(ssum, off);
    float pself = __expf(e_self - m);
    ssum += pself;
    float inv = 1.f / ssum;
    float w_l = p_l * inv;     // this lane's edge weight (first 64 edges)
    float wself = pself * inv;

    // ---- gather ----
    int grp = lane / FG;       // which edge within a load step
    int fg = lane % FG;        // which float4 of the row
    const float4* __restrict__ H4 = (const float4*)H;
    float4 hv = H4[(size_t)node * FG + fg];
    float ws0 = (grp == 0) ? wself : 0.f;
    float ax = ws0 * hv.x, ay = ws0 * hv.y, az = ws0 * hv.z, aw = ws0 * hv.w;

    int cnt = deg < 64 ? deg : 64;
    constexpr int STEP = 4 * GRP;              // edges per unrolled iter (4 loads)
    int cntr = (cnt + STEP - 1) / STEP * STEP; // cnt rounded up (<= 64)
#pragma unroll 1
    for (int i = 0; i < cntr; i += STEP) {
        int i0 = i + grp, i1 = i + GRP + grp, i2 = i + 2 * GRP + grp, i3 = i + 3 * GRP + grp;
        int s0 = __shfl(scol, i0), s1 = __shfl(scol, i1);
        int s2 = __shfl(scol, i2), s3 = __shfl(scol, i3);
        float w0 = __shfl(w_l, i0), w1 = __shfl(w_l, i1);
        float w2 = __shfl(w_l, i2), w3 = __shfl(w_l, i3);
        float4 g0 = H4[(size_t)s0 * FG + fg];
        float4 g1 = H4[(size_t)s1 * FG + fg];
        float4 g2 = H4[(size_t)s2 * FG + fg];
        float4 g3 = H4[(size_t)s3 * FG + fg];
        ax = fmaf(w0, g0.x, ax); ay = fmaf(w0, g0.y, ay);
        az = fmaf(w0, g0.z, az); aw = fmaf(w0, g0.w, aw);
        ax = fmaf(w1, g1.x, ax); ay = fmaf(w1, g1.y, ay);
        az = fmaf(w1, g1.z, az); aw = fmaf(w1, g1.w, aw);
        ax = fmaf(w2, g2.x, ax); ay = fmaf(w2, g2.y, ay);
        az = fmaf(w2, g2.z, az); aw = fmaf(w2, g2.w, aw);
        ax = fmaf(w3, g3.x, ax); ay = fmaf(w3, g3.y, ay);
        az = fmaf(w3, g3.z, az); aw = fmaf(w3, g3.w, aw);
    }
    for (int j = rs + 64; j < re; ++j) {  // rare: deg > 64
        int s = colv[j];
        float w = __expf(leaky(as_[s] + adi) - m) * inv;
        float we = (grp == 0) ? w : 0.f;
        float4 g = H4[(size_t)s * FG + fg];
        ax = fmaf(we, g.x, ax); ay = fmaf(we, g.y, ay);
        az = fmaf(we, g.z, az); aw = fmaf(we, g.w, aw);
    }
    // combine edge-groups (commutative float adds -> identical in all lanes)
#pragma unroll
    for (int off = FG; off < 64; off <<= 1) {
        ax += __shfl_xor(ax, off);
        ay += __shfl_xor(ay, off);
        az += __shfl_xor(az, off);
        aw += __shfl_xor(aw, off);
    }
    if (grp == 0) {
        float4 bv = ((const float4*)bias)[fg];
        ax += bv.x; ay += bv.y; az += bv.z; aw += bv.w;
        if (RELU) {
            ax = fmaxf(ax, 0.f); ay = fmaxf(ay, 0.f);
            az = fmaxf(az, 0.f); aw = fmaxf(aw, 0.f);
        }
        ((float4*)OUT)[(size_t)node * FG + fg] = make_float4(ax, ay, az, aw);
    }
}

// ---------------- host launch ----------------
extern "C" void kernel_launch(void* const* d_in, const int* in_sizes, int n_in,
                              void* d_out, int out_size, void* d_ws, size_t ws_size,
                              hipStream_t stream) {
    const float* x   = (const float*)d_in[0];
    const int*   ei  = (const int*)d_in[1];
    const float* W1  = (const float*)d_in[2];
    const float* a1s = (const float*)d_in[3];
    const float* a1d = (const float*)d_in[4];
    const float* b1  = (const float*)d_in[5];
    const float* W2  = (const float*)d_in[6];
    const float* a2s = (const float*)d_in[7];
    const float* a2d = (const float*)d_in[8];
    const float* b2  = (const float*)d_in[9];
    float* out = (float*)d_out;

    int N = in_sizes[0] / 128;   // 50000
    int E = in_sizes[1] / 2;     // 640000

    // workspace carve-up
    size_t off = 0;
    auto alloc = [&](size_t bytes) -> void* {
        off = (off + 255) & ~(size_t)255;
        void* p = (char*)d_ws + off;
        off += bytes;
        return p;
    };
    float* h      = (float*)alloc((size_t)N * 128 * 4);  // h1, reused as h2
    float* out1   = (float*)alloc((size_t)N * 128 * 4);
    float* as_    = (float*)alloc((size_t)N * 4);
    float* ad_    = (float*)alloc((size_t)N * 4);
    int* counts   = (int*)alloc((size_t)N * 4);
    int* rowptr   = (int*)alloc((size_t)(N + 1) * 4);
    int* fillpos  = (int*)alloc((size_t)N * 4);
    int* incl     = (int*)alloc((size_t)N * 4);
    int* bsums    = (int*)alloc(1024);
    int* colv     = (int*)alloc((size_t)E * 4);
    int* flag     = (int*)alloc(256);

    int blocksE = (E + 255) / 256;
    int NB = (N + 255) / 256;          // <= 256 required for single-block scan2
    int blocksN4 = (N + 3) / 4;
    int rowTiles = (N + 63) / 64;

    hipMemsetAsync(counts, 0, (size_t)N * 4, stream);
    int nchk = 2 * E < 512 ? 2 * E : 512;
    k_detect<<<1, 64, 0, stream>>>(ei, nchk, flag);
    k_count<<<blocksE, 256, 0, stream>>>(ei, flag, counts, E);
    k_scan1<<<NB, 256, 0, stream>>>(counts, incl, bsums, N);
    k_scan2<<<1, 256, 0, stream>>>(bsums, NB);
    k_scan3<<<NB, 256, 0, stream>>>(incl, bsums, counts, rowptr, fillpos, N);
    k_fill<<<blocksE, 256, 0, stream>>>(ei, flag, fillpos, colv, E);

    // layer 1: Fh = 128
    k_gemm<128><<<rowTiles * 2, 256, 0, stream>>>(x, W1, h, N);
    k_alpha<2><<<blocksN4, 256, 0, stream>>>(h, a1s, a1d, as_, ad_, N);
    k_agg<128, true><<<blocksN4, 256, 0, stream>>>(rowptr, colv, as_, ad_, h, b1, out1, N);

    // layer 2: Fout = 64 (h2 reuses h buffer)
    k_gemm<64><<<rowTiles, 256, 0, stream>>>(out1, W2, h, N);
    k_alpha<1><<<blocksN4, 256, 0, stream>>>(h, a2s, a2d, as_, ad_, N);
    k_agg<64, false><<<blocksN4, 256, 0, stream>>>(rowptr, colv, as_, ad_, h, b2, out, N);
}

// Round 6
// 214.737 us; speedup vs baseline: 1.7024x; 1.0760x over previous
//
#include <hip/hip_runtime.h>

#define LEAK 0.2f

static __device__ __forceinline__ float leaky(float e) { return e > 0.f ? e : LEAK * e; }

// bf16 helpers (RNE pack, cheap unpack)
static __device__ __forceinline__ unsigned f2bf(float f) {
    union { float f; unsigned u; } v; v.f = f;
    return (v.u + 0x7FFFu + ((v.u >> 16) & 1u)) >> 16;
}
static __device__ __forceinline__ float bflo(unsigned u) {
    union { unsigned x; float f; } v; v.x = u << 16; return v.f;
}
static __device__ __forceinline__ float bfhi(unsigned u) {
    union { unsigned x; float f; } v; v.x = u & 0xFFFF0000u; return v.f;
}

// ---------------- edge dtype detection (int64 vs int32) ----------------
__global__ void k_detect(const int* __restrict__ ei, int nwords_check, int* __restrict__ flag) {
    int lane = threadIdx.x;  // 64 lanes
    int bad = 0;
    for (int i = 1 + 2 * lane; i < nwords_check; i += 128) bad |= (ei[i] != 0);
    unsigned long long anybad = __ballot(bad != 0);
    if (lane == 0) *flag = (anybad == 0ULL) ? 1 : 0;  // 1 => int64 layout
}

// ---------------- CSR build ----------------
__global__ void k_count(const int* __restrict__ ei, const int* __restrict__ flag,
                        int* __restrict__ counts, int E) {
    int e = blockIdx.x * 256 + threadIdx.x;
    if (e >= E) return;
    int is64 = *flag;
    int d = is64 ? ei[(size_t)2 * E + 2 * e] : ei[(size_t)E + e];
    atomicAdd(&counts[d], 1);
}

__global__ void k_scan1(const int* __restrict__ counts, int* __restrict__ incl,
                        int* __restrict__ bsums, int n) {
    __shared__ int s[256];
    int t = threadIdx.x;
    int g = blockIdx.x * 256 + t;
    int v = (g < n) ? counts[g] : 0;
    s[t] = v;
    __syncthreads();
    for (int off = 1; off < 256; off <<= 1) {
        int add = (t >= off) ? s[t - off] : 0;
        __syncthreads();
        s[t] += add;
        __syncthreads();
    }
    if (g < n) incl[g] = s[t];
    if (t == 255) bsums[blockIdx.x] = s[255];
}

__global__ void k_scan2(int* __restrict__ bsums, int nb) {
    __shared__ int s[256];
    int t = threadIdx.x;
    int v = (t < nb) ? bsums[t] : 0;
    s[t] = v;
    __syncthreads();
    for (int off = 1; off < 256; off <<= 1) {
        int add = (t >= off) ? s[t - off] : 0;
        __syncthreads();
        s[t] += add;
        __syncthreads();
    }
    int excl = (t == 0) ? 0 : s[t - 1];
    if (t < nb) bsums[t] = excl;
}

// writes rowptr AND fillpos (exclusive prefix) in one pass
__global__ void k_scan3(const int* __restrict__ incl, const int* __restrict__ bsums,
                        const int* __restrict__ counts, int* __restrict__ rowptr,
                        int* __restrict__ fillpos, int n) {
    int g = blockIdx.x * 256 + threadIdx.x;
    if (g < n) {
        int inc = incl[g] + bsums[blockIdx.x];
        rowptr[g + 1] = inc;
        fillpos[g] = inc - counts[g];
    }
    if (g == 0) rowptr[0] = 0;
}

__global__ void k_fill(const int* __restrict__ ei, const int* __restrict__ flag,
                       int* __restrict__ fillpos, int* __restrict__ colv, int E) {
    int e = blockIdx.x * 256 + threadIdx.x;
    if (e >= E) return;
    int is64 = *flag;
    int s = is64 ? ei[2 * e] : ei[e];
    int d = is64 ? ei[(size_t)2 * E + 2 * e] : ei[(size_t)E + e];
    int p = atomicAdd(&fillpos[d], 1);
    colv[p] = s;
}

// ---------------- GEMM: Hb[n][F](bf16) = X[n][128](f32) @ W[128][F] ----------------
template <int F>
__global__ __launch_bounds__(256) void k_gemm(const float* __restrict__ X,
                                              const float* __restrict__ W,
                                              unsigned* __restrict__ Hb, int n) {
    constexpr int K = 128;
    constexpr int BM = 64, BN = 64;
    constexpr int XPAD = 132;
    __shared__ float xs[BM * XPAD];   // 33792 B
    __shared__ float ws[K * BN];      // 32768 B
    int t = threadIdx.x;
    constexpr int NB = F / BN;        // col-tiles
    int bm = blockIdx.x / NB;
    int bn = blockIdx.x % NB;
    long long row0 = (long long)bm * BM;

    // stage W tile [128][64]
    const float4* W4 = (const float4*)W;
    float4* ws4 = (float4*)ws;
#pragma unroll
    for (int i = t; i < K * (BN / 4); i += 256) {
        int k = i / (BN / 4), c4 = i % (BN / 4);
        ws4[k * (BN / 4) + c4] = W4[(size_t)k * (F / 4) + bn * (BN / 4) + c4];
    }
    // stage X tile [64][132] (padded row-major)
    const float4* X4 = (const float4*)X;
#pragma unroll
    for (int i = t; i < BM * (K / 4); i += 256) {
        int r = i / (K / 4), c4 = i % (K / 4);
        long long gr = row0 + r;
        float4 v = make_float4(0.f, 0.f, 0.f, 0.f);
        if (gr < n) v = X4[gr * (K / 4) + c4];
        *(float4*)&xs[r * XPAD + 4 * c4] = v;
    }
    __syncthreads();

    int tx = t & 15;   // col group (x4)
    int ty = t >> 4;   // row group (x4)

    float acc[4][4] = {};
    for (int kb = 0; kb < K; kb += 4) {
        float4 a[4], b[4];
#pragma unroll
        for (int i = 0; i < 4; ++i)
            a[i] = *(const float4*)&xs[(ty * 4 + i) * XPAD + kb];
#pragma unroll
        for (int j = 0; j < 4; ++j)
            b[j] = *(const float4*)&ws[(kb + j) * BN + tx * 4];
#pragma unroll
        for (int i = 0; i < 4; ++i) {
            acc[i][0] = fmaf(a[i].x, b[0].x, acc[i][0]);
            acc[i][1] = fmaf(a[i].x, b[0].y, acc[i][1]);
            acc[i][2] = fmaf(a[i].x, b[0].z, acc[i][2]);
            acc[i][3] = fmaf(a[i].x, b[0].w, acc[i][3]);
            acc[i][0] = fmaf(a[i].y, b[1].x, acc[i][0]);
            acc[i][1] = fmaf(a[i].y, b[1].y, acc[i][1]);
            acc[i][2] = fmaf(a[i].y, b[1].z, acc[i][2]);
            acc[i][3] = fmaf(a[i].y, b[1].w, acc[i][3]);
            acc[i][0] = fmaf(a[i].z, b[2].x, acc[i][0]);
            acc[i][1] = fmaf(a[i].z, b[2].y, acc[i][1]);
            acc[i][2] = fmaf(a[i].z, b[2].z, acc[i][2]);
            acc[i][3] = fmaf(a[i].z, b[2].w, acc[i][3]);
            acc[i][0] = fmaf(a[i].w, b[3].x, acc[i][0]);
            acc[i][1] = fmaf(a[i].w, b[3].y, acc[i][1]);
            acc[i][2] = fmaf(a[i].w, b[3].z, acc[i][2]);
            acc[i][3] = fmaf(a[i].w, b[3].w, acc[i][3]);
        }
    }

    // epilogue: pack to bf16 (2 per uint), 8B store per row
    int colu = bn * (BN / 2) + tx * 2;   // uint index within row (F/2 uints)
#pragma unroll
    for (int i = 0; i < 4; ++i) {
        long long gr = row0 + ty * 4 + i;
        if (gr < n) {
            unsigned p0 = f2bf(acc[i][0]) | (f2bf(acc[i][1]) << 16);
            unsigned p1 = f2bf(acc[i][2]) | (f2bf(acc[i][3]) << 16);
            *(uint2*)&Hb[gr * (F / 2) + colu] = make_uint2(p0, p1);
        }
    }
}

// ---------------- alpha_s / alpha_d: per-row dot products (bf16 H) ----------------
template <int F>
__global__ __launch_bounds__(256) void k_alpha(const unsigned* __restrict__ Hu,
                                               const float* __restrict__ asrc,
                                               const float* __restrict__ adst,
                                               float* __restrict__ out_s,
                                               float* __restrict__ out_d, int n) {
    constexpr int UPR = F / 2;  // uints per row (64 or 32)
    int node = blockIdx.x * 4 + (threadIdx.x >> 6);
    int lane = threadIdx.x & 63;
    if (node >= n) return;
    float ps = 0.f, pd = 0.f;
    if (lane < UPR) {
        unsigned u = Hu[(size_t)node * UPR + lane];
        float f0 = bflo(u), f1 = bfhi(u);
        float2 s2 = ((const float2*)asrc)[lane];
        float2 d2 = ((const float2*)adst)[lane];
        ps = f0 * s2.x + f1 * s2.y;
        pd = f0 * d2.x + f1 * d2.y;
    }
#pragma unroll
    for (int off = 32; off; off >>= 1) {
        ps += __shfl_xor(ps, off);
        pd += __shfl_xor(pd, off);
    }
    if (lane == 0) {
        out_s[node] = ps;
        out_d[node] = pd;
    }
}

// ---------------- fused segment softmax + aggregation (wave per dst node) ----------------
// Softmax phase: lane l holds edge (rs+l)'s src + weight in registers.
// Gather phase: 16B uint4 loads of bf16 rows (8 features/lane); wave split
// into GRP = 64/FG8 edge-groups so one load covers GRP edges (4 for F=128,
// 8 for F=64). Partial accumulators combined via shfl_xor (deterministic).
template <int F, bool RELU>
__global__ __launch_bounds__(256) void k_agg(const int* __restrict__ rowptr,
                                             const int* __restrict__ colv,
                                             const float* __restrict__ as_,
                                             const float* __restrict__ ad_,
                                             const unsigned* __restrict__ Hu,
                                             const float* __restrict__ bias,
                                             float* __restrict__ OUT, int n) {
    constexpr int FG8 = F / 8;       // uint4 slots per row (16 or 8)
    constexpr int GRP = 64 / FG8;    // edge-groups per wave (4 or 8)
    int node = blockIdx.x * 4 + (threadIdx.x >> 6);
    int lane = threadIdx.x & 63;
    if (node >= n) return;
    int rs = rowptr[node], re = rowptr[node + 1];
    int deg = re - rs;
    float adi = ad_[node];
    float e_self = leaky(as_[node] + adi);

    int scol = node;
    float e_l = -3.0e38f;
    if (lane < deg) {
        scol = colv[rs + lane];
        e_l = leaky(as_[scol] + adi);
    }
    float m = fmaxf(e_l, e_self);
    for (int base = 64; base < deg; base += 64) {  // rare: deg > 64
        if (base + lane < deg) m = fmaxf(m, leaky(as_[colv[rs + base + lane]] + adi));
    }
#pragma unroll
    for (int off = 32; off; off >>= 1) m = fmaxf(m, __shfl_xor(m, off));

    float p_l = (lane < deg) ? __expf(e_l - m) : 0.f;
    float ssum = p_l;
    for (int base = 64; base < deg; base += 64) {
        if (base + lane < deg) ssum += __expf(leaky(as_[colv[rs + base + lane]] + adi) - m);
    }
#pragma unroll
    for (int off = 32; off; off >>= 1) ssum += __shfl_xor(ssum, off);
    float pself = __expf(e_self - m);
    ssum += pself;
    float inv = 1.f / ssum;
    float w_l = p_l * inv;     // this lane's edge weight (first 64 edges)
    float wself = pself * inv;

    // ---- gather (bf16 rows as uint4 = 8 features) ----
    int grp = lane / FG8;      // which edge within a load step
    int fg = lane % FG8;       // which uint4 of the row
    const uint4* __restrict__ H16 = (const uint4*)Hu;
    float a0, a1, a2, a3, a4, a5, a6, a7;
    {
        uint4 hv = H16[(size_t)node * FG8 + fg];
        float ws0 = (grp == 0) ? wself : 0.f;
        a0 = ws0 * bflo(hv.x); a1 = ws0 * bfhi(hv.x);
        a2 = ws0 * bflo(hv.y); a3 = ws0 * bfhi(hv.y);
        a4 = ws0 * bflo(hv.z); a5 = ws0 * bfhi(hv.z);
        a6 = ws0 * bflo(hv.w); a7 = ws0 * bfhi(hv.w);
    }

    int cnt = deg < 64 ? deg : 64;
    constexpr int STEP = 4 * GRP;              // edges per unrolled iter (4 loads)
    int cntr = (cnt + STEP - 1) / STEP * STEP; // cnt rounded up (<= 64)
#pragma unroll 1
    for (int i = 0; i < cntr; i += STEP) {
        int i0 = i + grp, i1 = i + GRP + grp, i2 = i + 2 * GRP + grp, i3 = i + 3 * GRP + grp;
        int s0 = __shfl(scol, i0), s1 = __shfl(scol, i1);
        int s2 = __shfl(scol, i2), s3 = __shfl(scol, i3);
        float w0 = __shfl(w_l, i0), w1 = __shfl(w_l, i1);
        float w2 = __shfl(w_l, i2), w3 = __shfl(w_l, i3);
        uint4 g0 = H16[(size_t)s0 * FG8 + fg];
        uint4 g1 = H16[(size_t)s1 * FG8 + fg];
        uint4 g2 = H16[(size_t)s2 * FG8 + fg];
        uint4 g3 = H16[(size_t)s3 * FG8 + fg];
        a0 = fmaf(w0, bflo(g0.x), a0); a1 = fmaf(w0, bfhi(g0.x), a1);
        a2 = fmaf(w0, bflo(g0.y), a2); a3 = fmaf(w0, bfhi(g0.y), a3);
        a4 = fmaf(w0, bflo(g0.z), a4); a5 = fmaf(w0, bfhi(g0.z), a5);
        a6 = fmaf(w0, bflo(g0.w), a6); a7 = fmaf(w0, bfhi(g0.w), a7);
        a0 = fmaf(w1, bflo(g1.x), a0); a1 = fmaf(w1, bfhi(g1.x), a1);
        a2 = fmaf(w1, bflo(g1.y), a2); a3 = fmaf(w1, bfhi(g1.y), a3);
        a4 = fmaf(w1, bflo(g1.z), a4); a5 = fmaf(w1, bfhi(g1.z), a5);
        a6 = fmaf(w1, bflo(g1.w), a6); a7 = fmaf(w1, bfhi(g1.w), a7);
        a0 = fmaf(w2, bflo(g2.x), a0); a1 = fmaf(w2, bfhi(g2.x), a1);
        a2 = fmaf(w2, bflo(g2.y), a2); a3 = fmaf(w2, bfhi(g2.y), a3);
        a4 = fmaf(w2, bflo(g2.z), a4); a5 = fmaf(w2, bfhi(g2.z), a5);
        a6 = fmaf(w2, bflo(g2.w), a6); a7 = fmaf(w2, bfhi(g2.w), a7);
        a0 = fmaf(w3, bflo(g3.x), a0); a1 = fmaf(w3, bfhi(g3.x), a1);
        a2 = fmaf(w3, bflo(g3.y), a2); a3 = fmaf(w3, bfhi(g3.y), a3);
        a4 = fmaf(w3, bflo(g3.z), a4); a5 = fmaf(w3, bfhi(g3.z), a5);
        a6 = fmaf(w3, bflo(g3.w), a6); a7 = fmaf(w3, bfhi(g3.w), a7);
    }
    for (int j = rs + 64; j < re; ++j) {  // rare: deg > 64
        int s = colv[j];
        float w = __expf(leaky(as_[s] + adi) - m) * inv;
        float we = (grp == 0) ? w : 0.f;
        uint4 g = H16[(size_t)s * FG8 + fg];
        a0 = fmaf(we, bflo(g.x), a0); a1 = fmaf(we, bfhi(g.x), a1);
        a2 = fmaf(we, bflo(g.y), a2); a3 = fmaf(we, bfhi(g.y), a3);
        a4 = fmaf(we, bflo(g.z), a4); a5 = fmaf(we, bfhi(g.z), a5);
        a6 = fmaf(we, bflo(g.w), a6); a7 = fmaf(we, bfhi(g.w), a7);
    }
    // combine edge-groups (commutative float adds -> identical in all lanes)
#pragma unroll
    for (int off = FG8; off < 64; off <<= 1) {
        a0 += __shfl_xor(a0, off); a1 += __shfl_xor(a1, off);
        a2 += __shfl_xor(a2, off); a3 += __shfl_xor(a3, off);
        a4 += __shfl_xor(a4, off); a5 += __shfl_xor(a5, off);
        a6 += __shfl_xor(a6, off); a7 += __shfl_xor(a7, off);
    }
    if (grp == 0) {
        const float4* b4 = (const float4*)bias;
        float4 bv0 = b4[fg * 2], bv1 = b4[fg * 2 + 1];
        a0 += bv0.x; a1 += bv0.y; a2 += bv0.z; a3 += bv0.w;
        a4 += bv1.x; a5 += bv1.y; a6 += bv1.z; a7 += bv1.w;
        if (RELU) {
            a0 = fmaxf(a0, 0.f); a1 = fmaxf(a1, 0.f);
            a2 = fmaxf(a2, 0.f); a3 = fmaxf(a3, 0.f);
            a4 = fmaxf(a4, 0.f); a5 = fmaxf(a5, 0.f);
            a6 = fmaxf(a6, 0.f); a7 = fmaxf(a7, 0.f);
        }
        float4* o4 = (float4*)&OUT[(size_t)node * F + fg * 8];
        o4[0] = make_float4(a0, a1, a2, a3);
        o4[1] = make_float4(a4, a5, a6, a7);
    }
}

// ---------------- host launch ----------------
extern "C" void kernel_launch(void* const* d_in, const int* in_sizes, int n_in,
                              void* d_out, int out_size, void* d_ws, size_t ws_size,
                              hipStream_t stream) {
    const float* x   = (const float*)d_in[0];
    const int*   ei  = (const int*)d_in[1];
    const float* W1  = (const float*)d_in[2];
    const float* a1s = (const float*)d_in[3];
    const float* a1d = (const float*)d_in[4];
    const float* b1  = (const float*)d_in[5];
    const float* W2  = (const float*)d_in[6];
    const float* a2s = (const float*)d_in[7];
    const float* a2d = (const float*)d_in[8];
    const float* b2  = (const float*)d_in[9];
    float* out = (float*)d_out;

    int N = in_sizes[0] / 128;   // 50000
    int E = in_sizes[1] / 2;     // 640000

    // workspace carve-up
    size_t off = 0;
    auto alloc = [&](size_t bytes) -> void* {
        off = (off + 255) & ~(size_t)255;
        void* p = (char*)d_ws + off;
        off += bytes;
        return p;
    };
    unsigned* h   = (unsigned*)alloc((size_t)N * 64 * 4);  // bf16 h (N x 128), reused as h2
    float* out1   = (float*)alloc((size_t)N * 128 * 4);
    float* as_    = (float*)alloc((size_t)N * 4);
    float* ad_    = (float*)alloc((size_t)N * 4);
    int* counts   = (int*)alloc((size_t)N * 4);
    int* rowptr   = (int*)alloc((size_t)(N + 1) * 4);
    int* fillpos  = (int*)alloc((size_t)N * 4);
    int* incl     = (int*)alloc((size_t)N * 4);
    int* bsums    = (int*)alloc(1024);
    int* colv     = (int*)alloc((size_t)E * 4);
    int* flag     = (int*)alloc(256);

    int blocksE = (E + 255) / 256;
    int NB = (N + 255) / 256;          // <= 256 required for single-block scan2
    int blocksN4 = (N + 3) / 4;
    int rowTiles = (N + 63) / 64;

    hipMemsetAsync(counts, 0, (size_t)N * 4, stream);
    int nchk = 2 * E < 512 ? 2 * E : 512;
    k_detect<<<1, 64, 0, stream>>>(ei, nchk, flag);
    k_count<<<blocksE, 256, 0, stream>>>(ei, flag, counts, E);
    k_scan1<<<NB, 256, 0, stream>>>(counts, incl, bsums, N);
    k_scan2<<<1, 256, 0, stream>>>(bsums, NB);
    k_scan3<<<NB, 256, 0, stream>>>(incl, bsums, counts, rowptr, fillpos, N);
    k_fill<<<blocksE, 256, 0, stream>>>(ei, flag, fillpos, colv, E);

    // layer 1: Fh = 128
    k_gemm<128><<<rowTiles * 2, 256, 0, stream>>>(x, W1, h, N);
    k_alpha<128><<<blocksN4, 256, 0, stream>>>(h, a1s, a1d, as_, ad_, N);
    k_agg<128, true><<<blocksN4, 256, 0, stream>>>(rowptr, colv, as_, ad_, h, b1, out1, N);

    // layer 2: Fout = 64 (h2 reuses h buffer)
    k_gemm<64><<<rowTiles, 256, 0, stream>>>(out1, W2, h, N);
    k_alpha<64><<<blocksN4, 256, 0, stream>>>(h, a2s, a2d, as_, ad_, N);
    k_agg<64, false><<<blocksN4, 256, 0, stream>>>(rowptr, colv, as_, ad_, h, b2, out, N);
}

// Round 7
// 190.513 us; speedup vs baseline: 1.9189x; 1.1272x over previous
//
#include <hip/hip_runtime.h>

#define LEAK 0.2f

static __device__ __forceinline__ float leaky(float e) { return e > 0.f ? e : LEAK * e; }

// bf16 helpers (RNE pack, cheap unpack)
static __device__ __forceinline__ unsigned f2bf(float f) {
    union { float f; unsigned u; } v; v.f = f;
    return (v.u + 0x7FFFu + ((v.u >> 16) & 1u)) >> 16;
}
static __device__ __forceinline__ float bflo(unsigned u) {
    union { unsigned x; float f; } v; v.x = u << 16; return v.f;
}
static __device__ __forceinline__ float bfhi(unsigned u) {
    union { unsigned x; float f; } v; v.x = u & 0xFFFF0000u; return v.f;
}

using bf16x8 = __attribute__((ext_vector_type(8))) short;
using f32x4 = __attribute__((ext_vector_type(4))) float;

// ---------------- small utility kernels ----------------
__global__ void k_zero(int* __restrict__ p, int n) {
    int i = blockIdx.x * 256 + threadIdx.x;
    if (i < n) p[i] = 0;
}

__global__ void k_detect(const int* __restrict__ ei, int nwords_check, int* __restrict__ flag) {
    int lane = threadIdx.x;  // 64 lanes
    int bad = 0;
    for (int i = 1 + 2 * lane; i < nwords_check; i += 128) bad |= (ei[i] != 0);
    unsigned long long anybad = __ballot(bad != 0);
    if (lane == 0) *flag = (anybad == 0ULL) ? 1 : 0;  // 1 => int64 layout
}

// ---------------- CSR build ----------------
__global__ void k_count(const int* __restrict__ ei, const int* __restrict__ flag,
                        int* __restrict__ counts, int E) {
    int e = blockIdx.x * 256 + threadIdx.x;
    if (e >= E) return;
    int is64 = *flag;
    int d = is64 ? ei[(size_t)2 * E + 2 * e] : ei[(size_t)E + e];
    atomicAdd(&counts[d], 1);
}

__global__ void k_scan1(const int* __restrict__ counts, int* __restrict__ incl,
                        int* __restrict__ bsums, int n) {
    __shared__ int s[256];
    int t = threadIdx.x;
    int g = blockIdx.x * 256 + t;
    int v = (g < n) ? counts[g] : 0;
    s[t] = v;
    __syncthreads();
    for (int off = 1; off < 256; off <<= 1) {
        int add = (t >= off) ? s[t - off] : 0;
        __syncthreads();
        s[t] += add;
        __syncthreads();
    }
    if (g < n) incl[g] = s[t];
    if (t == 255) bsums[blockIdx.x] = s[255];
}

__global__ void k_scan2(int* __restrict__ bsums, int nb) {
    __shared__ int s[256];
    int t = threadIdx.x;
    int v = (t < nb) ? bsums[t] : 0;
    s[t] = v;
    __syncthreads();
    for (int off = 1; off < 256; off <<= 1) {
        int add = (t >= off) ? s[t - off] : 0;
        __syncthreads();
        s[t] += add;
        __syncthreads();
    }
    int excl = (t == 0) ? 0 : s[t - 1];
    if (t < nb) bsums[t] = excl;
}

__global__ void k_scan3(const int* __restrict__ incl, const int* __restrict__ bsums,
                        const int* __restrict__ counts, int* __restrict__ rowptr,
                        int* __restrict__ fillpos, int n) {
    int g = blockIdx.x * 256 + threadIdx.x;
    if (g < n) {
        int inc = incl[g] + bsums[blockIdx.x];
        rowptr[g + 1] = inc;
        fillpos[g] = inc - counts[g];
    }
    if (g == 0) rowptr[0] = 0;
}

__global__ void k_fill(const int* __restrict__ ei, const int* __restrict__ flag,
                       int* __restrict__ fillpos, int* __restrict__ colv, int E) {
    int e = blockIdx.x * 256 + threadIdx.x;
    if (e >= E) return;
    int is64 = *flag;
    int s = is64 ? ei[2 * e] : ei[e];
    int d = is64 ? ei[(size_t)2 * E + 2 * e] : ei[(size_t)E + e];
    int p = atomicAdd(&fillpos[d], 1);
    colv[p] = s;
}

// ---------------- MFMA GEMM: Hb[n][F](bf16) = A[n][128] @ W[128][F] ----------------
// 4 waves/block, 64 rows/block (16 per wave). W converted to bf16 and staged
// TRANSPOSED in LDS: wsT[ncol][K+8] so B-fragments are contiguous ds_read_b128
// (row stride 272 B = 16B-aligned; 16-lane group aliases 2-way = free).
// Fragment layouts (m89-verified family): A row=lane&15, k=(lane>>4)*8+i;
// B col=lane&15, same k; D col=lane&15, row=(lane>>4)*4+reg.
template <int F, bool AF32>
__global__ __launch_bounds__(256) void k_gemm_mfma(const void* __restrict__ Xv,
                                                   const float* __restrict__ W,
                                                   unsigned short* __restrict__ Hb, int n) {
    constexpr int K = 128;
    constexpr int KP = K + 8;       // padded row length (shorts)
    constexpr int NT = F / 16;      // 16-col tiles per wave stripe
    __shared__ unsigned short wsT[F * KP];
    int t = threadIdx.x;
    int w = t >> 6, lane = t & 63;
    int lrow = lane & 15, kg = lane >> 4;  // kg in 0..3
    long long row0 = (long long)blockIdx.x * 64;

    // stage W^T as bf16: W[k][F] (f32) -> wsT[c][k]
    for (int i = t; i < K * F / 4; i += 256) {
        int k = i / (F / 4), n4 = i % (F / 4);
        float4 v = ((const float4*)W)[(size_t)k * (F / 4) + n4];
        wsT[(4 * n4 + 0) * KP + k] = (unsigned short)f2bf(v.x);
        wsT[(4 * n4 + 1) * KP + k] = (unsigned short)f2bf(v.y);
        wsT[(4 * n4 + 2) * KP + k] = (unsigned short)f2bf(v.z);
        wsT[(4 * n4 + 3) * KP + k] = (unsigned short)f2bf(v.w);
    }
    __syncthreads();

    long long grow = row0 + w * 16 + lrow;
    bool rowok = grow < n;

    f32x4 acc[NT];
#pragma unroll
    for (int i = 0; i < NT; ++i) acc[i] = (f32x4){0.f, 0.f, 0.f, 0.f};

#pragma unroll
    for (int ks = 0; ks < K / 32; ++ks) {
        bf16x8 af;
        if constexpr (AF32) {
            const float* Xp = (const float*)Xv + grow * K + ks * 32 + kg * 8;
            float4 x0 = make_float4(0.f, 0.f, 0.f, 0.f), x1 = x0;
            if (rowok) {
                x0 = ((const float4*)Xp)[0];
                x1 = ((const float4*)Xp)[1];
            }
            af = (bf16x8){(short)f2bf(x0.x), (short)f2bf(x0.y), (short)f2bf(x0.z), (short)f2bf(x0.w),
                          (short)f2bf(x1.x), (short)f2bf(x1.y), (short)f2bf(x1.z), (short)f2bf(x1.w)};
        } else {
            uint4 u = make_uint4(0, 0, 0, 0);
            if (rowok) {
                const unsigned short* Xp = (const unsigned short*)Xv + grow * K + ks * 32 + kg * 8;
                u = *(const uint4*)Xp;
            }
            af = *(bf16x8*)&u;
        }
#pragma unroll
        for (int nt = 0; nt < NT; ++nt) {
            const unsigned short* bp = &wsT[(nt * 16 + lrow) * KP + ks * 32 + kg * 8];
            uint4 ub = *(const uint4*)bp;
            bf16x8 bf = *(bf16x8*)&ub;
            acc[nt] = __builtin_amdgcn_mfma_f32_16x16x32_bf16(af, bf, acc[nt], 0, 0, 0);
        }
    }

    // epilogue: D col=lane&15, row=(lane>>4)*4+reg -> bf16 scalar stores
    int r0 = w * 16 + kg * 4;
#pragma unroll
    for (int nt = 0; nt < NT; ++nt) {
        int c = nt * 16 + lrow;
#pragma unroll
        for (int i = 0; i < 4; ++i) {
            long long r = row0 + r0 + i;
            if (r < n) Hb[r * F + c] = (unsigned short)f2bf(acc[nt][i]);
        }
    }
}

// ---------------- alpha_s / alpha_d: per-row dot products (bf16 H) ----------------
template <int F>
__global__ __launch_bounds__(256) void k_alpha(const unsigned* __restrict__ Hu,
                                               const float* __restrict__ asrc,
                                               const float* __restrict__ adst,
                                               float* __restrict__ out_s,
                                               float* __restrict__ out_d, int n) {
    constexpr int UPR = F / 2;  // uints per row (64 or 32)
    int node = blockIdx.x * 4 + (threadIdx.x >> 6);
    int lane = threadIdx.x & 63;
    if (node >= n) return;
    float ps = 0.f, pd = 0.f;
    if (lane < UPR) {
        unsigned u = Hu[(size_t)node * UPR + lane];
        float f0 = bflo(u), f1 = bfhi(u);
        float2 s2 = ((const float2*)asrc)[lane];
        float2 d2 = ((const float2*)adst)[lane];
        ps = f0 * s2.x + f1 * s2.y;
        pd = f0 * d2.x + f1 * d2.y;
    }
#pragma unroll
    for (int off = 32; off; off >>= 1) {
        ps += __shfl_xor(ps, off);
        pd += __shfl_xor(pd, off);
    }
    if (lane == 0) {
        out_s[node] = ps;
        out_d[node] = pd;
    }
}

// ---------------- fused segment softmax + aggregation (wave per dst node) ----------------
// OB: true -> output packed bf16 (uint4/row-chunk), false -> f32.
template <int F, bool RELU, bool OB>
__global__ __launch_bounds__(256) void k_agg(const int* __restrict__ rowptr,
                                             const int* __restrict__ colv,
                                             const float* __restrict__ as_,
                                             const float* __restrict__ ad_,
                                             const unsigned* __restrict__ Hu,
                                             const float* __restrict__ bias,
                                             void* __restrict__ OUT, int n) {
    constexpr int FG8 = F / 8;       // uint4 slots per row (16 or 8)
    constexpr int GRP = 64 / FG8;    // edge-groups per wave (4 or 8)
    int node = blockIdx.x * 4 + (threadIdx.x >> 6);
    int lane = threadIdx.x & 63;
    if (node >= n) return;
    int rs = rowptr[node], re = rowptr[node + 1];
    int deg = re - rs;
    float adi = ad_[node];
    float e_self = leaky(as_[node] + adi);

    int scol = node;
    float e_l = -3.0e38f;
    if (lane < deg) {
        scol = colv[rs + lane];
        e_l = leaky(as_[scol] + adi);
    }
    float m = fmaxf(e_l, e_self);
    for (int base = 64; base < deg; base += 64) {  // rare: deg > 64
        if (base + lane < deg) m = fmaxf(m, leaky(as_[colv[rs + base + lane]] + adi));
    }
#pragma unroll
    for (int off = 32; off; off >>= 1) m = fmaxf(m, __shfl_xor(m, off));

    float p_l = (lane < deg) ? __expf(e_l - m) : 0.f;
    float ssum = p_l;
    for (int base = 64; base < deg; base += 64) {
        if (base + lane < deg) ssum += __expf(leaky(as_[colv[rs + base + lane]] + adi) - m);
    }
#pragma unroll
    for (int off = 32; off; off >>= 1) ssum += __shfl_xor(ssum, off);
    float pself = __expf(e_self - m);
    ssum += pself;
    float inv = 1.f / ssum;
    float w_l = p_l * inv;     // this lane's edge weight (first 64 edges)
    float wself = pself * inv;

    // ---- gather (bf16 rows as uint4 = 8 features) ----
    int grp = lane / FG8;      // which edge within a load step
    int fg = lane % FG8;       // which uint4 of the row
    const uint4* __restrict__ H16 = (const uint4*)Hu;
    float a0, a1, a2, a3, a4, a5, a6, a7;
    {
        uint4 hv = H16[(size_t)node * FG8 + fg];
        float ws0 = (grp == 0) ? wself : 0.f;
        a0 = ws0 * bflo(hv.x); a1 = ws0 * bfhi(hv.x);
        a2 = ws0 * bflo(hv.y); a3 = ws0 * bfhi(hv.y);
        a4 = ws0 * bflo(hv.z); a5 = ws0 * bfhi(hv.z);
        a6 = ws0 * bflo(hv.w); a7 = ws0 * bfhi(hv.w);
    }

    int cnt = deg < 64 ? deg : 64;
    constexpr int STEP = 4 * GRP;              // edges per unrolled iter (4 loads)
    int cntr = (cnt + STEP - 1) / STEP * STEP; // cnt rounded up (<= 64)
#pragma unroll 1
    for (int i = 0; i < cntr; i += STEP) {
        int i0 = i + grp, i1 = i + GRP + grp, i2 = i + 2 * GRP + grp, i3 = i + 3 * GRP + grp;
        int s0 = __shfl(scol, i0), s1 = __shfl(scol, i1);
        int s2 = __shfl(scol, i2), s3 = __shfl(scol, i3);
        float w0 = __shfl(w_l, i0), w1 = __shfl(w_l, i1);
        float w2 = __shfl(w_l, i2), w3 = __shfl(w_l, i3);
        uint4 g0 = H16[(size_t)s0 * FG8 + fg];
        uint4 g1 = H16[(size_t)s1 * FG8 + fg];
        uint4 g2 = H16[(size_t)s2 * FG8 + fg];
        uint4 g3 = H16[(size_t)s3 * FG8 + fg];
        a0 = fmaf(w0, bflo(g0.x), a0); a1 = fmaf(w0, bfhi(g0.x), a1);
        a2 = fmaf(w0, bflo(g0.y), a2); a3 = fmaf(w0, bfhi(g0.y), a3);
        a4 = fmaf(w0, bflo(g0.z), a4); a5 = fmaf(w0, bfhi(g0.z), a5);
        a6 = fmaf(w0, bflo(g0.w), a6); a7 = fmaf(w0, bfhi(g0.w), a7);
        a0 = fmaf(w1, bflo(g1.x), a0); a1 = fmaf(w1, bfhi(g1.x), a1);
        a2 = fmaf(w1, bflo(g1.y), a2); a3 = fmaf(w1, bfhi(g1.y), a3);
        a4 = fmaf(w1, bflo(g1.z), a4); a5 = fmaf(w1, bfhi(g1.z), a5);
        a6 = fmaf(w1, bflo(g1.w), a6); a7 = fmaf(w1, bfhi(g1.w), a7);
        a0 = fmaf(w2, bflo(g2.x), a0); a1 = fmaf(w2, bfhi(g2.x), a1);
        a2 = fmaf(w2, bflo(g2.y), a2); a3 = fmaf(w2, bfhi(g2.y), a3);
        a4 = fmaf(w2, bflo(g2.z), a4); a5 = fmaf(w2, bfhi(g2.z), a5);
        a6 = fmaf(w2, bflo(g2.w), a6); a7 = fmaf(w2, bfhi(g2.w), a7);
        a0 = fmaf(w3, bflo(g3.x), a0); a1 = fmaf(w3, bfhi(g3.x), a1);
        a2 = fmaf(w3, bflo(g3.y), a2); a3 = fmaf(w3, bfhi(g3.y), a3);
        a4 = fmaf(w3, bflo(g3.z), a4); a5 = fmaf(w3, bfhi(g3.z), a5);
        a6 = fmaf(w3, bflo(g3.w), a6); a7 = fmaf(w3, bfhi(g3.w), a7);
    }
    for (int j = rs + 64; j < re; ++j) {  // rare: deg > 64
        int s = colv[j];
        float w = __expf(leaky(as_[s] + adi) - m) * inv;
        float we = (grp == 0) ? w : 0.f;
        uint4 g = H16[(size_t)s * FG8 + fg];
        a0 = fmaf(we, bflo(g.x), a0); a1 = fmaf(we, bfhi(g.x), a1);
        a2 = fmaf(we, bflo(g.y), a2); a3 = fmaf(we, bfhi(g.y), a3);
        a4 = fmaf(we, bflo(g.z), a4); a5 = fmaf(we, bfhi(g.z), a5);
        a6 = fmaf(we, bflo(g.w), a6); a7 = fmaf(we, bfhi(g.w), a7);
    }
    // combine edge-groups (commutative float adds -> identical in all lanes)
#pragma unroll
    for (int off = FG8; off < 64; off <<= 1) {
        a0 += __shfl_xor(a0, off); a1 += __shfl_xor(a1, off);
        a2 += __shfl_xor(a2, off); a3 += __shfl_xor(a3, off);
        a4 += __shfl_xor(a4, off); a5 += __shfl_xor(a5, off);
        a6 += __shfl_xor(a6, off); a7 += __shfl_xor(a7, off);
    }
    if (grp == 0) {
        const float4* b4 = (const float4*)bias;
        float4 bv0 = b4[fg * 2], bv1 = b4[fg * 2 + 1];
        a0 += bv0.x; a1 += bv0.y; a2 += bv0.z; a3 += bv0.w;
        a4 += bv1.x; a5 += bv1.y; a6 += bv1.z; a7 += bv1.w;
        if (RELU) {
            a0 = fmaxf(a0, 0.f); a1 = fmaxf(a1, 0.f);
            a2 = fmaxf(a2, 0.f); a3 = fmaxf(a3, 0.f);
            a4 = fmaxf(a4, 0.f); a5 = fmaxf(a5, 0.f);
            a6 = fmaxf(a6, 0.f); a7 = fmaxf(a7, 0.f);
        }
        if (OB) {
            uint4 p;
            p.x = f2bf(a0) | (f2bf(a1) << 16);
            p.y = f2bf(a2) | (f2bf(a3) << 16);
            p.z = f2bf(a4) | (f2bf(a5) << 16);
            p.w = f2bf(a6) | (f2bf(a7) << 16);
            ((uint4*)OUT)[(size_t)node * FG8 + fg] = p;
        } else {
            float4* o4 = (float4*)((float*)OUT + (size_t)node * F + fg * 8);
            o4[0] = make_float4(a0, a1, a2, a3);
            o4[1] = make_float4(a4, a5, a6, a7);
        }
    }
}

// ---------------- host launch ----------------
extern "C" void kernel_launch(void* const* d_in, const int* in_sizes, int n_in,
                              void* d_out, int out_size, void* d_ws, size_t ws_size,
                              hipStream_t stream) {
    const float* x   = (const float*)d_in[0];
    const int*   ei  = (const int*)d_in[1];
    const float* W1  = (const float*)d_in[2];
    const float* a1s = (const float*)d_in[3];
    const float* a1d = (const float*)d_in[4];
    const float* b1  = (const float*)d_in[5];
    const float* W2  = (const float*)d_in[6];
    const float* a2s = (const float*)d_in[7];
    const float* a2d = (const float*)d_in[8];
    const float* b2  = (const float*)d_in[9];
    float* out = (float*)d_out;

    int N = in_sizes[0] / 128;   // 50000
    int E = in_sizes[1] / 2;     // 640000

    // workspace carve-up
    size_t off = 0;
    auto alloc = [&](size_t bytes) -> void* {
        off = (off + 255) & ~(size_t)255;
        void* p = (char*)d_ws + off;
        off += bytes;
        return p;
    };
    unsigned short* h = (unsigned short*)alloc((size_t)N * 128 * 2);  // bf16 h1 / h2
    unsigned short* out1b = (unsigned short*)alloc((size_t)N * 128 * 2);  // bf16 out1
    float* as_    = (float*)alloc((size_t)N * 4);
    float* ad_    = (float*)alloc((size_t)N * 4);
    int* counts   = (int*)alloc((size_t)N * 4);
    int* rowptr   = (int*)alloc((size_t)(N + 1) * 4);
    int* fillpos  = (int*)alloc((size_t)N * 4);
    int* incl     = (int*)alloc((size_t)N * 4);
    int* bsums    = (int*)alloc(1024);
    int* colv     = (int*)alloc((size_t)E * 4);
    int* flag     = (int*)alloc(256);

    int blocksE = (E + 255) / 256;
    int NB = (N + 255) / 256;          // <= 256 required for single-block scan2
    int blocksN4 = (N + 3) / 4;
    int rowTiles = (N + 63) / 64;

    k_zero<<<NB, 256, 0, stream>>>(counts, N);
    int nchk = 2 * E < 512 ? 2 * E : 512;
    k_detect<<<1, 64, 0, stream>>>(ei, nchk, flag);
    k_count<<<blocksE, 256, 0, stream>>>(ei, flag, counts, E);
    k_scan1<<<NB, 256, 0, stream>>>(counts, incl, bsums, N);
    k_scan2<<<1, 256, 0, stream>>>(bsums, NB);
    k_scan3<<<NB, 256, 0, stream>>>(incl, bsums, counts, rowptr, fillpos, N);
    k_fill<<<blocksE, 256, 0, stream>>>(ei, flag, fillpos, colv, E);

    // layer 1: Fh = 128 (A = x f32, converted in-register)
    k_gemm_mfma<128, true><<<rowTiles, 256, 0, stream>>>(x, W1, h, N);
    k_alpha<128><<<blocksN4, 256, 0, stream>>>((const unsigned*)h, a1s, a1d, as_, ad_, N);
    k_agg<128, true, true><<<blocksN4, 256, 0, stream>>>(rowptr, colv, as_, ad_,
                                                         (const unsigned*)h, b1, out1b, N);

    // layer 2: Fout = 64 (A = out1b bf16)
    k_gemm_mfma<64, false><<<rowTiles, 256, 0, stream>>>(out1b, W2, h, N);
    k_alpha<64><<<blocksN4, 256, 0, stream>>>((const unsigned*)h, a2s, a2d, as_, ad_, N);
    k_agg<64, false, false><<<blocksN4, 256, 0, stream>>>(rowptr, colv, as_, ad_,
                                                          (const unsigned*)h, b2, out, N);
}

// Round 8
// 164.484 us; speedup vs baseline: 2.2226x; 1.1582x over previous
//
#include <hip/hip_runtime.h>

#define LEAK 0.2f

static __device__ __forceinline__ float leaky(float e) { return e > 0.f ? e : LEAK * e; }

// bf16 helpers (RNE pack, cheap unpack)
static __device__ __forceinline__ unsigned f2bf(float f) {
    union { float f; unsigned u; } v; v.f = f;
    return (v.u + 0x7FFFu + ((v.u >> 16) & 1u)) >> 16;
}
static __device__ __forceinline__ float bflo(unsigned u) {
    union { unsigned x; float f; } v; v.x = u << 16; return v.f;
}
static __device__ __forceinline__ float bfhi(unsigned u) {
    union { unsigned x; float f; } v; v.x = u & 0xFFFF0000u; return v.f;
}

using bf16x8 = __attribute__((ext_vector_type(8))) short;
using f32x4 = __attribute__((ext_vector_type(4))) float;

// ---------------- prep: zero counts + detect edge dtype + pre-transpose W1/W2 ----------------
// block 0: detect int64-vs-int32; blocks 1..NB: zero counts;
// blocks NB+1..NB+4: W1 transpose quarters; NB+5..NB+6: W2 transpose halves.
// Wt layout: [F][K] bf16 (row-major, K=128) so GEMM can stage it linearly.
__global__ __launch_bounds__(256) void k_prep(int* __restrict__ counts, int n,
                                              const int* __restrict__ ei, int nwords_check,
                                              int* __restrict__ flag,
                                              const float* __restrict__ W1,
                                              unsigned short* __restrict__ Wt1,
                                              const float* __restrict__ W2,
                                              unsigned short* __restrict__ Wt2, int NB) {
    int bid = blockIdx.x;
    int t = threadIdx.x;
    if (bid == 0) {
        if (t < 64) {
            int bad = 0;
            for (int i = 1 + 2 * t; i < nwords_check; i += 128) bad |= (ei[i] != 0);
            unsigned long long anybad = __ballot(bad != 0);
            if (t == 0) *flag = (anybad == 0ULL) ? 1 : 0;  // 1 => int64 layout
        }
        return;
    }
    if (bid <= NB) {
        int i = (bid - 1) * 256 + t;
        if (i < n) counts[i] = 0;
        return;
    }
    if (bid <= NB + 4) {                 // W1: 128x128, quarter q covers 32 k
        int q = bid - (NB + 1);
        int c = t & 127, ksub = t >> 7;  // ksub 0..1
        int k0 = q * 32 + ksub * 16;
        union { unsigned short s[16]; uint4 v[2]; } u;
#pragma unroll
        for (int j = 0; j < 16; ++j) u.s[j] = (unsigned short)f2bf(W1[(size_t)(k0 + j) * 128 + c]);
        uint4* dst = (uint4*)(Wt1 + (size_t)c * 128 + k0);
        dst[0] = u.v[0];
        dst[1] = u.v[1];
        return;
    }
    {                                    // W2: 128x64, half q covers 64 k
        int q = bid - (NB + 5);
        int c = t & 63, ksub = t >> 6;   // ksub 0..3
        int k0 = q * 64 + ksub * 16;
        union { unsigned short s[16]; uint4 v[2]; } u;
#pragma unroll
        for (int j = 0; j < 16; ++j) u.s[j] = (unsigned short)f2bf(W2[(size_t)(k0 + j) * 64 + c]);
        uint4* dst = (uint4*)(Wt2 + (size_t)c * 128 + k0);
        dst[0] = u.v[0];
        dst[1] = u.v[1];
        return;
    }
}

// ---------------- CSR build ----------------
__global__ void k_count(const int* __restrict__ ei, const int* __restrict__ flag,
                        int* __restrict__ counts, int E) {
    int e = blockIdx.x * 256 + threadIdx.x;
    if (e >= E) return;
    int is64 = *flag;
    int d = is64 ? ei[(size_t)2 * E + 2 * e] : ei[(size_t)E + e];
    atomicAdd(&counts[d], 1);
}

__global__ void k_scan1(const int* __restrict__ counts, int* __restrict__ incl,
                        int* __restrict__ bsums, int n) {
    __shared__ int s[256];
    int t = threadIdx.x;
    int g = blockIdx.x * 256 + t;
    int v = (g < n) ? counts[g] : 0;
    s[t] = v;
    __syncthreads();
    for (int off = 1; off < 256; off <<= 1) {
        int add = (t >= off) ? s[t - off] : 0;
        __syncthreads();
        s[t] += add;
        __syncthreads();
    }
    if (g < n) incl[g] = s[t];
    if (t == 255) bsums[blockIdx.x] = s[255];
}

__global__ void k_scan2(int* __restrict__ bsums, int nb) {
    __shared__ int s[256];
    int t = threadIdx.x;
    int v = (t < nb) ? bsums[t] : 0;
    s[t] = v;
    __syncthreads();
    for (int off = 1; off < 256; off <<= 1) {
        int add = (t >= off) ? s[t - off] : 0;
        __syncthreads();
        s[t] += add;
        __syncthreads();
    }
    int excl = (t == 0) ? 0 : s[t - 1];
    if (t < nb) bsums[t] = excl;
}

__global__ void k_scan3(const int* __restrict__ incl, const int* __restrict__ bsums,
                        const int* __restrict__ counts, int* __restrict__ rowptr,
                        int* __restrict__ fillpos, int n) {
    int g = blockIdx.x * 256 + threadIdx.x;
    if (g < n) {
        int inc = incl[g] + bsums[blockIdx.x];
        rowptr[g + 1] = inc;
        fillpos[g] = inc - counts[g];
    }
    if (g == 0) rowptr[0] = 0;
}

__global__ void k_fill(const int* __restrict__ ei, const int* __restrict__ flag,
                       int* __restrict__ fillpos, int* __restrict__ colv, int E) {
    int e = blockIdx.x * 256 + threadIdx.x;
    if (e >= E) return;
    int is64 = *flag;
    int s = is64 ? ei[2 * e] : ei[e];
    int d = is64 ? ei[(size_t)2 * E + 2 * e] : ei[(size_t)E + e];
    int p = atomicAdd(&fillpos[d], 1);
    colv[p] = s;
}

// ---------------- MFMA GEMM + fused alpha ----------------
// Hb[n][F](bf16) = A[n][128] @ W[128][F];  as_/ad_[r] = dot(H[r], asrc/adst)
// 4 waves/block, 64 rows/block (16 per wave). Wt ([F][K] bf16, pre-transposed)
// staged to LDS with linear uint4 writes (conflict-free); B-fragments are
// ds_read_b128 from padded rows (KP=136 shorts, 2-way alias = free).
// Fragment layouts (m89-verified): A row=lane&15, k=(lane>>4)*8+i;
// B col=lane&15, same k; D col=lane&15, row=(lane>>4)*4+reg.
// Alpha: per-row dot from f32 acc, shfl_xor reduce over the 16-lane lrow group.
template <int F, bool AF32>
__global__ __launch_bounds__(256) void k_gemm_mfma(const void* __restrict__ Xv,
                                                   const unsigned short* __restrict__ Wt,
                                                   const float* __restrict__ asrc,
                                                   const float* __restrict__ adst,
                                                   unsigned short* __restrict__ Hb,
                                                   float* __restrict__ out_s,
                                                   float* __restrict__ out_d, int n) {
    constexpr int K = 128;
    constexpr int KP = K + 8;       // padded row length (shorts)
    constexpr int NT = F / 16;      // 16-col tiles per wave stripe
    __shared__ unsigned short wsT[F * KP];
    int t = threadIdx.x;
    int w = t >> 6, lane = t & 63;
    int lrow = lane & 15, kg = lane >> 4;  // kg in 0..3
    long long row0 = (long long)blockIdx.x * 64;

    // stage Wt -> LDS (linear uint4 writes into padded rows)
#pragma unroll
    for (int i = t; i < F * (K / 8); i += 256) {
        int c = i / (K / 8), j8 = i % (K / 8);
        uint4 v = ((const uint4*)(Wt + (size_t)c * K))[j8];
        *(uint4*)&wsT[c * KP + 8 * j8] = v;
    }
    __syncthreads();

    long long grow = row0 + w * 16 + lrow;
    bool rowok = grow < n;

    f32x4 acc[NT];
#pragma unroll
    for (int i = 0; i < NT; ++i) acc[i] = (f32x4){0.f, 0.f, 0.f, 0.f};

#pragma unroll
    for (int ks = 0; ks < K / 32; ++ks) {
        bf16x8 af;
        if constexpr (AF32) {
            const float* Xp = (const float*)Xv + grow * K + ks * 32 + kg * 8;
            float4 x0 = make_float4(0.f, 0.f, 0.f, 0.f), x1 = x0;
            if (rowok) {
                x0 = ((const float4*)Xp)[0];
                x1 = ((const float4*)Xp)[1];
            }
            af = (bf16x8){(short)f2bf(x0.x), (short)f2bf(x0.y), (short)f2bf(x0.z), (short)f2bf(x0.w),
                          (short)f2bf(x1.x), (short)f2bf(x1.y), (short)f2bf(x1.z), (short)f2bf(x1.w)};
        } else {
            uint4 u = make_uint4(0, 0, 0, 0);
            if (rowok) {
                const unsigned short* Xp = (const unsigned short*)Xv + grow * K + ks * 32 + kg * 8;
                u = *(const uint4*)Xp;
            }
            af = *(bf16x8*)&u;
        }
#pragma unroll
        for (int nt = 0; nt < NT; ++nt) {
            const unsigned short* bp = &wsT[(nt * 16 + lrow) * KP + ks * 32 + kg * 8];
            uint4 ub = *(const uint4*)bp;
            bf16x8 bf = *(bf16x8*)&ub;
            acc[nt] = __builtin_amdgcn_mfma_f32_16x16x32_bf16(af, bf, acc[nt], 0, 0, 0);
        }
    }

    // fused alpha: per-row dots from f32 acc
    {
        float ps[4] = {0.f, 0.f, 0.f, 0.f}, pd[4] = {0.f, 0.f, 0.f, 0.f};
#pragma unroll
        for (int nt = 0; nt < NT; ++nt) {
            float asv = asrc[nt * 16 + lrow];
            float adv = adst[nt * 16 + lrow];
#pragma unroll
            for (int i = 0; i < 4; ++i) {
                ps[i] = fmaf(acc[nt][i], asv, ps[i]);
                pd[i] = fmaf(acc[nt][i], adv, pd[i]);
            }
        }
#pragma unroll
        for (int off = 1; off < 16; off <<= 1) {
#pragma unroll
            for (int i = 0; i < 4; ++i) {
                ps[i] += __shfl_xor(ps[i], off);
                pd[i] += __shfl_xor(pd[i], off);
            }
        }
        if (lrow == 0) {
#pragma unroll
            for (int i = 0; i < 4; ++i) {
                long long r = row0 + w * 16 + kg * 4 + i;
                if (r < n) {
                    out_s[r] = ps[i];
                    out_d[r] = pd[i];
                }
            }
        }
    }

    // epilogue: D col=lane&15, row=(lane>>4)*4+reg -> bf16 scalar stores
    int r0 = w * 16 + kg * 4;
#pragma unroll
    for (int nt = 0; nt < NT; ++nt) {
        int c = nt * 16 + lrow;
#pragma unroll
        for (int i = 0; i < 4; ++i) {
            long long r = row0 + r0 + i;
            if (r < n) Hb[r * F + c] = (unsigned short)f2bf(acc[nt][i]);
        }
    }
}

// ---------------- fused segment softmax + aggregation (wave per dst node) ----------------
// OB: true -> output packed bf16 (uint4/row-chunk), false -> f32.
template <int F, bool RELU, bool OB>
__global__ __launch_bounds__(256) void k_agg(const int* __restrict__ rowptr,
                                             const int* __restrict__ colv,
                                             const float* __restrict__ as_,
                                             const float* __restrict__ ad_,
                                             const unsigned* __restrict__ Hu,
                                             const float* __restrict__ bias,
                                             void* __restrict__ OUT, int n) {
    constexpr int FG8 = F / 8;       // uint4 slots per row (16 or 8)
    constexpr int GRP = 64 / FG8;    // edge-groups per wave (4 or 8)
    int node = blockIdx.x * 4 + (threadIdx.x >> 6);
    int lane = threadIdx.x & 63;
    if (node >= n) return;
    int rs = rowptr[node], re = rowptr[node + 1];
    int deg = re - rs;
    float adi = ad_[node];
    float e_self = leaky(as_[node] + adi);

    int scol = node;
    float e_l = -3.0e38f;
    if (lane < deg) {
        scol = colv[rs + lane];
        e_l = leaky(as_[scol] + adi);
    }
    float m = fmaxf(e_l, e_self);
    for (int base = 64; base < deg; base += 64) {  // rare: deg > 64
        if (base + lane < deg) m = fmaxf(m, leaky(as_[colv[rs + base + lane]] + adi));
    }
#pragma unroll
    for (int off = 32; off; off >>= 1) m = fmaxf(m, __shfl_xor(m, off));

    float p_l = (lane < deg) ? __expf(e_l - m) : 0.f;
    float ssum = p_l;
    for (int base = 64; base < deg; base += 64) {
        if (base + lane < deg) ssum += __expf(leaky(as_[colv[rs + base + lane]] + adi) - m);
    }
#pragma unroll
    for (int off = 32; off; off >>= 1) ssum += __shfl_xor(ssum, off);
    float pself = __expf(e_self - m);
    ssum += pself;
    float inv = 1.f / ssum;
    float w_l = p_l * inv;     // this lane's edge weight (first 64 edges)
    float wself = pself * inv;

    // ---- gather (bf16 rows as uint4 = 8 features) ----
    int grp = lane / FG8;      // which edge within a load step
    int fg = lane % FG8;       // which uint4 of the row
    const uint4* __restrict__ H16 = (const uint4*)Hu;
    float a0, a1, a2, a3, a4, a5, a6, a7;
    {
        uint4 hv = H16[(size_t)node * FG8 + fg];
        float ws0 = (grp == 0) ? wself : 0.f;
        a0 = ws0 * bflo(hv.x); a1 = ws0 * bfhi(hv.x);
        a2 = ws0 * bflo(hv.y); a3 = ws0 * bfhi(hv.y);
        a4 = ws0 * bflo(hv.z); a5 = ws0 * bfhi(hv.z);
        a6 = ws0 * bflo(hv.w); a7 = ws0 * bfhi(hv.w);
    }

    int cnt = deg < 64 ? deg : 64;
    constexpr int STEP = 4 * GRP;              // edges per unrolled iter (4 loads)
    int cntr = (cnt + STEP - 1) / STEP * STEP; // cnt rounded up (<= 64)
#pragma unroll 1
    for (int i = 0; i < cntr; i += STEP) {
        int i0 = i + grp, i1 = i + GRP + grp, i2 = i + 2 * GRP + grp, i3 = i + 3 * GRP + grp;
        int s0 = __shfl(scol, i0), s1 = __shfl(scol, i1);
        int s2 = __shfl(scol, i2), s3 = __shfl(scol, i3);
        float w0 = __shfl(w_l, i0), w1 = __shfl(w_l, i1);
        float w2 = __shfl(w_l, i2), w3 = __shfl(w_l, i3);
        uint4 g0 = H16[(size_t)s0 * FG8 + fg];
        uint4 g1 = H16[(size_t)s1 * FG8 + fg];
        uint4 g2 = H16[(size_t)s2 * FG8 + fg];
        uint4 g3 = H16[(size_t)s3 * FG8 + fg];
        a0 = fmaf(w0, bflo(g0.x), a0); a1 = fmaf(w0, bfhi(g0.x), a1);
        a2 = fmaf(w0, bflo(g0.y), a2); a3 = fmaf(w0, bfhi(g0.y), a3);
        a4 = fmaf(w0, bflo(g0.z), a4); a5 = fmaf(w0, bfhi(g0.z), a5);
        a6 = fmaf(w0, bflo(g0.w), a6); a7 = fmaf(w0, bfhi(g0.w), a7);
        a0 = fmaf(w1, bflo(g1.x), a0); a1 = fmaf(w1, bfhi(g1.x), a1);
        a2 = fmaf(w1, bflo(g1.y), a2); a3 = fmaf(w1, bfhi(g1.y), a3);
        a4 = fmaf(w1, bflo(g1.z), a4); a5 = fmaf(w1, bfhi(g1.z), a5);
        a6 = fmaf(w1, bflo(g1.w), a6); a7 = fmaf(w1, bfhi(g1.w), a7);
        a0 = fmaf(w2, bflo(g2.x), a0); a1 = fmaf(w2, bfhi(g2.x), a1);
        a2 = fmaf(w2, bflo(g2.y), a2); a3 = fmaf(w2, bfhi(g2.y), a3);
        a4 = fmaf(w2, bflo(g2.z), a4); a5 = fmaf(w2, bfhi(g2.z), a5);
        a6 = fmaf(w2, bflo(g2.w), a6); a7 = fmaf(w2, bfhi(g2.w), a7);
        a0 = fmaf(w3, bflo(g3.x), a0); a1 = fmaf(w3, bfhi(g3.x), a1);
        a2 = fmaf(w3, bflo(g3.y), a2); a3 = fmaf(w3, bfhi(g3.y), a3);
        a4 = fmaf(w3, bflo(g3.z), a4); a5 = fmaf(w3, bfhi(g3.z), a5);
        a6 = fmaf(w3, bflo(g3.w), a6); a7 = fmaf(w3, bfhi(g3.w), a7);
    }
    for (int j = rs + 64; j < re; ++j) {  // rare: deg > 64
        int s = colv[j];
        float w = __expf(leaky(as_[s] + adi) - m) * inv;
        float we = (grp == 0) ? w : 0.f;
        uint4 g = H16[(size_t)s * FG8 + fg];
        a0 = fmaf(we, bflo(g.x), a0); a1 = fmaf(we, bfhi(g.x), a1);
        a2 = fmaf(we, bflo(g.y), a2); a3 = fmaf(we, bfhi(g.y), a3);
        a4 = fmaf(we, bflo(g.z), a4); a5 = fmaf(we, bfhi(g.z), a5);
        a6 = fmaf(we, bflo(g.w), a6); a7 = fmaf(we, bfhi(g.w), a7);
    }
    // combine edge-groups (commutative float adds -> identical in all lanes)
#pragma unroll
    for (int off = FG8; off < 64; off <<= 1) {
        a0 += __shfl_xor(a0, off); a1 += __shfl_xor(a1, off);
        a2 += __shfl_xor(a2, off); a3 += __shfl_xor(a3, off);
        a4 += __shfl_xor(a4, off); a5 += __shfl_xor(a5, off);
        a6 += __shfl_xor(a6, off); a7 += __shfl_xor(a7, off);
    }
    if (grp == 0) {
        const float4* b4 = (const float4*)bias;
        float4 bv0 = b4[fg * 2], bv1 = b4[fg * 2 + 1];
        a0 += bv0.x; a1 += bv0.y; a2 += bv0.z; a3 += bv0.w;
        a4 += bv1.x; a5 += bv1.y; a6 += bv1.z; a7 += bv1.w;
        if (RELU) {
            a0 = fmaxf(a0, 0.f); a1 = fmaxf(a1, 0.f);
            a2 = fmaxf(a2, 0.f); a3 = fmaxf(a3, 0.f);
            a4 = fmaxf(a4, 0.f); a5 = fmaxf(a5, 0.f);
            a6 = fmaxf(a6, 0.f); a7 = fmaxf(a7, 0.f);
        }
        if (OB) {
            uint4 p;
            p.x = f2bf(a0) | (f2bf(a1) << 16);
            p.y = f2bf(a2) | (f2bf(a3) << 16);
            p.z = f2bf(a4) | (f2bf(a5) << 16);
            p.w = f2bf(a6) | (f2bf(a7) << 16);
            ((uint4*)OUT)[(size_t)node * FG8 + fg] = p;
        } else {
            float4* o4 = (float4*)((float*)OUT + (size_t)node * F + fg * 8);
            o4[0] = make_float4(a0, a1, a2, a3);
            o4[1] = make_float4(a4, a5, a6, a7);
        }
    }
}

// ---------------- host launch ----------------
extern "C" void kernel_launch(void* const* d_in, const int* in_sizes, int n_in,
                              void* d_out, int out_size, void* d_ws, size_t ws_size,
                              hipStream_t stream) {
    const float* x   = (const float*)d_in[0];
    const int*   ei  = (const int*)d_in[1];
    const float* W1  = (const float*)d_in[2];
    const float* a1s = (const float*)d_in[3];
    const float* a1d = (const float*)d_in[4];
    const float* b1  = (const float*)d_in[5];
    const float* W2  = (const float*)d_in[6];
    const float* a2s = (const float*)d_in[7];
    const float* a2d = (const float*)d_in[8];
    const float* b2  = (const float*)d_in[9];
    float* out = (float*)d_out;

    int N = in_sizes[0] / 128;   // 50000
    int E = in_sizes[1] / 2;     // 640000

    // workspace carve-up
    size_t off = 0;
    auto alloc = [&](size_t bytes) -> void* {
        off = (off + 255) & ~(size_t)255;
        void* p = (char*)d_ws + off;
        off += bytes;
        return p;
    };
    unsigned short* h = (unsigned short*)alloc((size_t)N * 128 * 2);      // bf16 h1 / h2
    unsigned short* out1b = (unsigned short*)alloc((size_t)N * 128 * 2);  // bf16 out1
    unsigned short* Wt1 = (unsigned short*)alloc(128 * 128 * 2);
    unsigned short* Wt2 = (unsigned short*)alloc(64 * 128 * 2);
    float* as_    = (float*)alloc((size_t)N * 4);
    float* ad_    = (float*)alloc((size_t)N * 4);
    int* counts   = (int*)alloc((size_t)N * 4);
    int* rowptr   = (int*)alloc((size_t)(N + 1) * 4);
    int* fillpos  = (int*)alloc((size_t)N * 4);
    int* incl     = (int*)alloc((size_t)N * 4);
    int* bsums    = (int*)alloc(1024);
    int* colv     = (int*)alloc((size_t)E * 4);
    int* flag     = (int*)alloc(256);

    int blocksE = (E + 255) / 256;
    int NB = (N + 255) / 256;          // <= 256 required for single-block scan2
    int blocksN4 = (N + 3) / 4;
    int rowTiles = (N + 63) / 64;

    int nchk = 2 * E < 512 ? 2 * E : 512;
    k_prep<<<NB + 7, 256, 0, stream>>>(counts, N, ei, nchk, flag, W1, Wt1, W2, Wt2, NB);
    k_count<<<blocksE, 256, 0, stream>>>(ei, flag, counts, E);
    k_scan1<<<NB, 256, 0, stream>>>(counts, incl, bsums, N);
    k_scan2<<<1, 256, 0, stream>>>(bsums, NB);
    k_scan3<<<NB, 256, 0, stream>>>(incl, bsums, counts, rowptr, fillpos, N);
    k_fill<<<blocksE, 256, 0, stream>>>(ei, flag, fillpos, colv, E);

    // layer 1: Fh = 128 (A = x f32, converted in-register); alpha fused
    k_gemm_mfma<128, true><<<rowTiles, 256, 0, stream>>>(x, Wt1, a1s, a1d, h, as_, ad_, N);
    k_agg<128, true, true><<<blocksN4, 256, 0, stream>>>(rowptr, colv, as_, ad_,
                                                         (const unsigned*)h, b1, out1b, N);

    // layer 2: Fout = 64 (A = out1b bf16); alpha fused
    k_gemm_mfma<64, false><<<rowTiles, 256, 0, stream>>>(out1b, Wt2, a2s, a2d, h, as_, ad_, N);
    k_agg<64, false, false><<<blocksN4, 256, 0, stream>>>(rowptr, colv, as_, ad_,
                                                          (const unsigned*)h, b2, out, N);
}

// Round 9
// 139.697 us; speedup vs baseline: 2.6169x; 1.1774x over previous
//
#include <hip/hip_runtime.h>

#define LEAK 0.2f

static __device__ __forceinline__ float leaky(float e) { return e > 0.f ? e : LEAK * e; }

// bf16 helpers (RNE pack, cheap unpack)
static __device__ __forceinline__ unsigned f2bf(float f) {
    union { float f; unsigned u; } v; v.f = f;
    return (v.u + 0x7FFFu + ((v.u >> 16) & 1u)) >> 16;
}
static __device__ __forceinline__ float bflo(unsigned u) {
    union { unsigned x; float f; } v; v.x = u << 16; return v.f;
}
static __device__ __forceinline__ float bfhi(unsigned u) {
    union { unsigned x; float f; } v; v.x = u & 0xFFFF0000u; return v.f;
}

using bf16x8 = __attribute__((ext_vector_type(8))) short;
using f32x4 = __attribute__((ext_vector_type(4))) float;

// ---------------- prep: zero counts + detect edge dtype + pre-transpose W1/W2 ----------------
__global__ __launch_bounds__(256) void k_prep(int* __restrict__ counts, int n,
                                              const int* __restrict__ ei, int nwords_check,
                                              int* __restrict__ flag,
                                              const float* __restrict__ W1,
                                              unsigned short* __restrict__ Wt1,
                                              const float* __restrict__ W2,
                                              unsigned short* __restrict__ Wt2, int NB) {
    int bid = blockIdx.x;
    int t = threadIdx.x;
    if (bid == 0) {
        if (t < 64) {
            int bad = 0;
            for (int i = 1 + 2 * t; i < nwords_check; i += 128) bad |= (ei[i] != 0);
            unsigned long long anybad = __ballot(bad != 0);
            if (t == 0) *flag = (anybad == 0ULL) ? 1 : 0;  // 1 => int64 layout
        }
        return;
    }
    if (bid <= NB) {
        int i = (bid - 1) * 256 + t;
        if (i < n) counts[i] = 0;
        return;
    }
    if (bid <= NB + 4) {                 // W1: 128x128, quarter q covers 32 k
        int q = bid - (NB + 1);
        int c = t & 127, ksub = t >> 7;  // ksub 0..1
        int k0 = q * 32 + ksub * 16;
        union { unsigned short s[16]; uint4 v[2]; } u;
#pragma unroll
        for (int j = 0; j < 16; ++j) u.s[j] = (unsigned short)f2bf(W1[(size_t)(k0 + j) * 128 + c]);
        uint4* dst = (uint4*)(Wt1 + (size_t)c * 128 + k0);
        dst[0] = u.v[0];
        dst[1] = u.v[1];
        return;
    }
    {                                    // W2: 128x64, half q covers 64 k
        int q = bid - (NB + 5);
        int c = t & 63, ksub = t >> 6;   // ksub 0..3
        int k0 = q * 64 + ksub * 16;
        union { unsigned short s[16]; uint4 v[2]; } u;
#pragma unroll
        for (int j = 0; j < 16; ++j) u.s[j] = (unsigned short)f2bf(W2[(size_t)(k0 + j) * 64 + c]);
        uint4* dst = (uint4*)(Wt2 + (size_t)c * 128 + k0);
        dst[0] = u.v[0];
        dst[1] = u.v[1];
        return;
    }
}

// ---------------- CSR build: rank (single atomic pass) + scans + place ----------------
// k_rank: r = atomicAdd(counts[d]) is edge's rank within its dst segment.
// 4 edges/thread: independent atomic chains (latency hiding), int4 coalesced
// stores of rank/src/dst (also decodes int64 edge_index exactly once).
__global__ __launch_bounds__(256) void k_rank(const int* __restrict__ ei,
                                              const int* __restrict__ flag,
                                              int* __restrict__ counts,
                                              int* __restrict__ rank_,
                                              int* __restrict__ srcv,
                                              int* __restrict__ dstv, int E) {
    int base = (blockIdx.x * 256 + threadIdx.x) * 4;
    if (base >= E) return;
    int is64 = *flag;
    if (base + 3 < E) {
        int s0, s1, s2, s3, d0, d1, d2, d3;
        if (is64) {
            const uint4* ps = (const uint4*)(ei + 2 * (size_t)base);
            uint4 a = ps[0], b = ps[1];
            const uint4* pd = (const uint4*)(ei + 2 * ((size_t)E + base));
            uint4 c = pd[0], e4 = pd[1];
            s0 = a.x; s1 = a.z; s2 = b.x; s3 = b.z;
            d0 = c.x; d1 = c.z; d2 = e4.x; d3 = e4.z;
        } else {
            int4 a = *(const int4*)(ei + base);
            int4 b = *(const int4*)(ei + (size_t)E + base);
            s0 = a.x; s1 = a.y; s2 = a.z; s3 = a.w;
            d0 = b.x; d1 = b.y; d2 = b.z; d3 = b.w;
        }
        int r0 = atomicAdd(&counts[d0], 1);
        int r1 = atomicAdd(&counts[d1], 1);
        int r2 = atomicAdd(&counts[d2], 1);
        int r3 = atomicAdd(&counts[d3], 1);
        *(int4*)(rank_ + base) = make_int4(r0, r1, r2, r3);
        *(int4*)(srcv + base) = make_int4(s0, s1, s2, s3);
        *(int4*)(dstv + base) = make_int4(d0, d1, d2, d3);
    } else {
        for (int j = 0; j < 4 && base + j < E; ++j) {
            int e = base + j;
            int ss = is64 ? ei[2 * (size_t)e] : ei[e];
            int dd = is64 ? ei[2 * ((size_t)E + e)] : ei[(size_t)E + e];
            int r = atomicAdd(&counts[dd], 1);
            rank_[e] = r;
            srcv[e] = ss;
            dstv[e] = dd;
        }
    }
}

__global__ void k_scan1(const int* __restrict__ counts, int* __restrict__ incl,
                        int* __restrict__ bsums, int n) {
    __shared__ int s[256];
    int t = threadIdx.x;
    int g = blockIdx.x * 256 + t;
    int v = (g < n) ? counts[g] : 0;
    s[t] = v;
    __syncthreads();
    for (int off = 1; off < 256; off <<= 1) {
        int add = (t >= off) ? s[t - off] : 0;
        __syncthreads();
        s[t] += add;
        __syncthreads();
    }
    if (g < n) incl[g] = s[t];
    if (t == 255) bsums[blockIdx.x] = s[255];
}

__global__ void k_scan2(int* __restrict__ bsums, int nb) {
    __shared__ int s[256];
    int t = threadIdx.x;
    int v = (t < nb) ? bsums[t] : 0;
    s[t] = v;
    __syncthreads();
    for (int off = 1; off < 256; off <<= 1) {
        int add = (t >= off) ? s[t - off] : 0;
        __syncthreads();
        s[t] += add;
        __syncthreads();
    }
    int excl = (t == 0) ? 0 : s[t - 1];
    if (t < nb) bsums[t] = excl;
}

__global__ void k_scan3(const int* __restrict__ incl, const int* __restrict__ bsums,
                        int* __restrict__ rowptr, int n) {
    int g = blockIdx.x * 256 + threadIdx.x;
    if (g < n) rowptr[g + 1] = incl[g] + bsums[blockIdx.x];
    if (g == 0) rowptr[0] = 0;
}

// k_place: colv[rowptr[d]+r] = s. No atomics; 4 independent scatters/thread.
__global__ __launch_bounds__(256) void k_place(const int* __restrict__ rank_,
                                               const int* __restrict__ srcv,
                                               const int* __restrict__ dstv,
                                               const int* __restrict__ rowptr,
                                               int* __restrict__ colv, int E) {
    int base = (blockIdx.x * 256 + threadIdx.x) * 4;
    if (base >= E) return;
    if (base + 3 < E) {
        int4 r = *(const int4*)(rank_ + base);
        int4 s = *(const int4*)(srcv + base);
        int4 d = *(const int4*)(dstv + base);
        int p0 = rowptr[d.x] + r.x;
        int p1 = rowptr[d.y] + r.y;
        int p2 = rowptr[d.z] + r.z;
        int p3 = rowptr[d.w] + r.w;
        colv[p0] = s.x;
        colv[p1] = s.y;
        colv[p2] = s.z;
        colv[p3] = s.w;
    } else {
        for (int j = 0; j < 4 && base + j < E; ++j) {
            int e = base + j;
            colv[rowptr[dstv[e]] + rank_[e]] = srcv[e];
        }
    }
}

// ---------------- MFMA GEMM + fused alpha ----------------
template <int F, bool AF32>
__global__ __launch_bounds__(256) void k_gemm_mfma(const void* __restrict__ Xv,
                                                   const unsigned short* __restrict__ Wt,
                                                   const float* __restrict__ asrc,
                                                   const float* __restrict__ adst,
                                                   unsigned short* __restrict__ Hb,
                                                   float* __restrict__ out_s,
                                                   float* __restrict__ out_d, int n) {
    constexpr int K = 128;
    constexpr int KP = K + 8;       // padded row length (shorts)
    constexpr int NT = F / 16;      // 16-col tiles per wave stripe
    __shared__ unsigned short wsT[F * KP];
    int t = threadIdx.x;
    int w = t >> 6, lane = t & 63;
    int lrow = lane & 15, kg = lane >> 4;  // kg in 0..3
    long long row0 = (long long)blockIdx.x * 64;

    // stage Wt -> LDS (linear uint4 writes into padded rows)
#pragma unroll
    for (int i = t; i < F * (K / 8); i += 256) {
        int c = i / (K / 8), j8 = i % (K / 8);
        uint4 v = ((const uint4*)(Wt + (size_t)c * K))[j8];
        *(uint4*)&wsT[c * KP + 8 * j8] = v;
    }
    __syncthreads();

    long long grow = row0 + w * 16 + lrow;
    bool rowok = grow < n;

    f32x4 acc[NT];
#pragma unroll
    for (int i = 0; i < NT; ++i) acc[i] = (f32x4){0.f, 0.f, 0.f, 0.f};

#pragma unroll
    for (int ks = 0; ks < K / 32; ++ks) {
        bf16x8 af;
        if constexpr (AF32) {
            const float* Xp = (const float*)Xv + grow * K + ks * 32 + kg * 8;
            float4 x0 = make_float4(0.f, 0.f, 0.f, 0.f), x1 = x0;
            if (rowok) {
                x0 = ((const float4*)Xp)[0];
                x1 = ((const float4*)Xp)[1];
            }
            af = (bf16x8){(short)f2bf(x0.x), (short)f2bf(x0.y), (short)f2bf(x0.z), (short)f2bf(x0.w),
                          (short)f2bf(x1.x), (short)f2bf(x1.y), (short)f2bf(x1.z), (short)f2bf(x1.w)};
        } else {
            uint4 u = make_uint4(0, 0, 0, 0);
            if (rowok) {
                const unsigned short* Xp = (const unsigned short*)Xv + grow * K + ks * 32 + kg * 8;
                u = *(const uint4*)Xp;
            }
            af = *(bf16x8*)&u;
        }
#pragma unroll
        for (int nt = 0; nt < NT; ++nt) {
            const unsigned short* bp = &wsT[(nt * 16 + lrow) * KP + ks * 32 + kg * 8];
            uint4 ub = *(const uint4*)bp;
            bf16x8 bf = *(bf16x8*)&ub;
            acc[nt] = __builtin_amdgcn_mfma_f32_16x16x32_bf16(af, bf, acc[nt], 0, 0, 0);
        }
    }

    // fused alpha: per-row dots from f32 acc
    {
        float ps[4] = {0.f, 0.f, 0.f, 0.f}, pd[4] = {0.f, 0.f, 0.f, 0.f};
#pragma unroll
        for (int nt = 0; nt < NT; ++nt) {
            float asv = asrc[nt * 16 + lrow];
            float adv = adst[nt * 16 + lrow];
#pragma unroll
            for (int i = 0; i < 4; ++i) {
                ps[i] = fmaf(acc[nt][i], asv, ps[i]);
                pd[i] = fmaf(acc[nt][i], adv, pd[i]);
            }
        }
#pragma unroll
        for (int off = 1; off < 16; off <<= 1) {
#pragma unroll
            for (int i = 0; i < 4; ++i) {
                ps[i] += __shfl_xor(ps[i], off);
                pd[i] += __shfl_xor(pd[i], off);
            }
        }
        if (lrow == 0) {
#pragma unroll
            for (int i = 0; i < 4; ++i) {
                long long r = row0 + w * 16 + kg * 4 + i;
                if (r < n) {
                    out_s[r] = ps[i];
                    out_d[r] = pd[i];
                }
            }
        }
    }

    // epilogue: D col=lane&15, row=(lane>>4)*4+reg -> bf16 scalar stores
    int r0 = w * 16 + kg * 4;
#pragma unroll
    for (int nt = 0; nt < NT; ++nt) {
        int c = nt * 16 + lrow;
#pragma unroll
        for (int i = 0; i < 4; ++i) {
            long long r = row0 + r0 + i;
            if (r < n) Hb[r * F + c] = (unsigned short)f2bf(acc[nt][i]);
        }
    }
}

// ---------------- fused segment softmax + aggregation (wave per dst node) ----------------
template <int F, bool RELU, bool OB>
__global__ __launch_bounds__(256) void k_agg(const int* __restrict__ rowptr,
                                             const int* __restrict__ colv,
                                             const float* __restrict__ as_,
                                             const float* __restrict__ ad_,
                                             const unsigned* __restrict__ Hu,
                                             const float* __restrict__ bias,
                                             void* __restrict__ OUT, int n) {
    constexpr int FG8 = F / 8;       // uint4 slots per row (16 or 8)
    constexpr int GRP = 64 / FG8;    // edge-groups per wave (4 or 8)
    int node = blockIdx.x * 4 + (threadIdx.x >> 6);
    int lane = threadIdx.x & 63;
    if (node >= n) return;
    int rs = rowptr[node], re = rowptr[node + 1];
    int deg = re - rs;
    float adi = ad_[node];
    float e_self = leaky(as_[node] + adi);

    int scol = node;
    float e_l = -3.0e38f;
    if (lane < deg) {
        scol = colv[rs + lane];
        e_l = leaky(as_[scol] + adi);
    }
    float m = fmaxf(e_l, e_self);
    for (int base = 64; base < deg; base += 64) {  // rare: deg > 64
        if (base + lane < deg) m = fmaxf(m, leaky(as_[colv[rs + base + lane]] + adi));
    }
#pragma unroll
    for (int off = 32; off; off >>= 1) m = fmaxf(m, __shfl_xor(m, off));

    float p_l = (lane < deg) ? __expf(e_l - m) : 0.f;
    float ssum = p_l;
    for (int base = 64; base < deg; base += 64) {
        if (base + lane < deg) ssum += __expf(leaky(as_[colv[rs + base + lane]] + adi) - m);
    }
#pragma unroll
    for (int off = 32; off; off >>= 1) ssum += __shfl_xor(ssum, off);
    float pself = __expf(e_self - m);
    ssum += pself;
    float inv = 1.f / ssum;
    float w_l = p_l * inv;     // this lane's edge weight (first 64 edges)
    float wself = pself * inv;

    // ---- gather (bf16 rows as uint4 = 8 features) ----
    int grp = lane / FG8;      // which edge within a load step
    int fg = lane % FG8;       // which uint4 of the row
    const uint4* __restrict__ H16 = (const uint4*)Hu;
    float a0, a1, a2, a3, a4, a5, a6, a7;
    {
        uint4 hv = H16[(size_t)node * FG8 + fg];
        float ws0 = (grp == 0) ? wself : 0.f;
        a0 = ws0 * bflo(hv.x); a1 = ws0 * bfhi(hv.x);
        a2 = ws0 * bflo(hv.y); a3 = ws0 * bfhi(hv.y);
        a4 = ws0 * bflo(hv.z); a5 = ws0 * bfhi(hv.z);
        a6 = ws0 * bflo(hv.w); a7 = ws0 * bfhi(hv.w);
    }

    int cnt = deg < 64 ? deg : 64;
    constexpr int STEP = 4 * GRP;              // edges per unrolled iter (4 loads)
    int cntr = (cnt + STEP - 1) / STEP * STEP; // cnt rounded up (<= 64)
#pragma unroll 1
    for (int i = 0; i < cntr; i += STEP) {
        int i0 = i + grp, i1 = i + GRP + grp, i2 = i + 2 * GRP + grp, i3 = i + 3 * GRP + grp;
        int s0 = __shfl(scol, i0), s1 = __shfl(scol, i1);
        int s2 = __shfl(scol, i2), s3 = __shfl(scol, i3);
        float w0 = __shfl(w_l, i0), w1 = __shfl(w_l, i1);
        float w2 = __shfl(w_l, i2), w3 = __shfl(w_l, i3);
        uint4 g0 = H16[(size_t)s0 * FG8 + fg];
        uint4 g1 = H16[(size_t)s1 * FG8 + fg];
        uint4 g2 = H16[(size_t)s2 * FG8 + fg];
        uint4 g3 = H16[(size_t)s3 * FG8 + fg];
        a0 = fmaf(w0, bflo(g0.x), a0); a1 = fmaf(w0, bfhi(g0.x), a1);
        a2 = fmaf(w0, bflo(g0.y), a2); a3 = fmaf(w0, bfhi(g0.y), a3);
        a4 = fmaf(w0, bflo(g0.z), a4); a5 = fmaf(w0, bfhi(g0.z), a5);
        a6 = fmaf(w0, bflo(g0.w), a6); a7 = fmaf(w0, bfhi(g0.w), a7);
        a0 = fmaf(w1, bflo(g1.x), a0); a1 = fmaf(w1, bfhi(g1.x), a1);
        a2 = fmaf(w1, bflo(g1.y), a2); a3 = fmaf(w1, bfhi(g1.y), a3);
        a4 = fmaf(w1, bflo(g1.z), a4); a5 = fmaf(w1, bfhi(g1.z), a5);
        a6 = fmaf(w1, bflo(g1.w), a6); a7 = fmaf(w1, bfhi(g1.w), a7);
        a0 = fmaf(w2, bflo(g2.x), a0); a1 = fmaf(w2, bfhi(g2.x), a1);
        a2 = fmaf(w2, bflo(g2.y), a2); a3 = fmaf(w2, bfhi(g2.y), a3);
        a4 = fmaf(w2, bflo(g2.z), a4); a5 = fmaf(w2, bfhi(g2.z), a5);
        a6 = fmaf(w2, bflo(g2.w), a6); a7 = fmaf(w2, bfhi(g2.w), a7);
        a0 = fmaf(w3, bflo(g3.x), a0); a1 = fmaf(w3, bfhi(g3.x), a1);
        a2 = fmaf(w3, bflo(g3.y), a2); a3 = fmaf(w3, bfhi(g3.y), a3);
        a4 = fmaf(w3, bflo(g3.z), a4); a5 = fmaf(w3, bfhi(g3.z), a5);
        a6 = fmaf(w3, bflo(g3.w), a6); a7 = fmaf(w3, bfhi(g3.w), a7);
    }
    for (int j = rs + 64; j < re; ++j) {  // rare: deg > 64
        int s = colv[j];
        float w = __expf(leaky(as_[s] + adi) - m) * inv;
        float we = (grp == 0) ? w : 0.f;
        uint4 g = H16[(size_t)s * FG8 + fg];
        a0 = fmaf(we, bflo(g.x), a0); a1 = fmaf(we, bfhi(g.x), a1);
        a2 = fmaf(we, bflo(g.y), a2); a3 = fmaf(we, bfhi(g.y), a3);
        a4 = fmaf(we, bflo(g.z), a4); a5 = fmaf(we, bfhi(g.z), a5);
        a6 = fmaf(we, bflo(g.w), a6); a7 = fmaf(we, bfhi(g.w), a7);
    }
    // combine edge-groups (commutative float adds -> identical in all lanes)
#pragma unroll
    for (int off = FG8; off < 64; off <<= 1) {
        a0 += __shfl_xor(a0, off); a1 += __shfl_xor(a1, off);
        a2 += __shfl_xor(a2, off); a3 += __shfl_xor(a3, off);
        a4 += __shfl_xor(a4, off); a5 += __shfl_xor(a5, off);
        a6 += __shfl_xor(a6, off); a7 += __shfl_xor(a7, off);
    }
    if (grp == 0) {
        const float4* b4 = (const float4*)bias;
        float4 bv0 = b4[fg * 2], bv1 = b4[fg * 2 + 1];
        a0 += bv0.x; a1 += bv0.y; a2 += bv0.z; a3 += bv0.w;
        a4 += bv1.x; a5 += bv1.y; a6 += bv1.z; a7 += bv1.w;
        if (RELU) {
            a0 = fmaxf(a0, 0.f); a1 = fmaxf(a1, 0.f);
            a2 = fmaxf(a2, 0.f); a3 = fmaxf(a3, 0.f);
            a4 = fmaxf(a4, 0.f); a5 = fmaxf(a5, 0.f);
            a6 = fmaxf(a6, 0.f); a7 = fmaxf(a7, 0.f);
        }
        if (OB) {
            uint4 p;
            p.x = f2bf(a0) | (f2bf(a1) << 16);
            p.y = f2bf(a2) | (f2bf(a3) << 16);
            p.z = f2bf(a4) | (f2bf(a5) << 16);
            p.w = f2bf(a6) | (f2bf(a7) << 16);
            ((uint4*)OUT)[(size_t)node * FG8 + fg] = p;
        } else {
            float4* o4 = (float4*)((float*)OUT + (size_t)node * F + fg * 8);
            o4[0] = make_float4(a0, a1, a2, a3);
            o4[1] = make_float4(a4, a5, a6, a7);
        }
    }
}

// ---------------- host launch ----------------
extern "C" void kernel_launch(void* const* d_in, const int* in_sizes, int n_in,
                              void* d_out, int out_size, void* d_ws, size_t ws_size,
                              hipStream_t stream) {
    const float* x   = (const float*)d_in[0];
    const int*   ei  = (const int*)d_in[1];
    const float* W1  = (const float*)d_in[2];
    const float* a1s = (const float*)d_in[3];
    const float* a1d = (const float*)d_in[4];
    const float* b1  = (const float*)d_in[5];
    const float* W2  = (const float*)d_in[6];
    const float* a2s = (const float*)d_in[7];
    const float* a2d = (const float*)d_in[8];
    const float* b2  = (const float*)d_in[9];
    float* out = (float*)d_out;

    int N = in_sizes[0] / 128;   // 50000
    int E = in_sizes[1] / 2;     // 640000

    // workspace carve-up
    size_t off = 0;
    auto alloc = [&](size_t bytes) -> void* {
        off = (off + 255) & ~(size_t)255;
        void* p = (char*)d_ws + off;
        off += bytes;
        return p;
    };
    unsigned short* h = (unsigned short*)alloc((size_t)N * 128 * 2);      // bf16 h1 / h2
    unsigned short* out1b = (unsigned short*)alloc((size_t)N * 128 * 2);  // bf16 out1
    unsigned short* Wt1 = (unsigned short*)alloc(128 * 128 * 2);
    unsigned short* Wt2 = (unsigned short*)alloc(64 * 128 * 2);
    float* as_    = (float*)alloc((size_t)N * 4);
    float* ad_    = (float*)alloc((size_t)N * 4);
    int* counts   = (int*)alloc((size_t)N * 4);
    int* rowptr   = (int*)alloc((size_t)(N + 1) * 4);
    int* incl     = (int*)alloc((size_t)N * 4);
    int* bsums    = (int*)alloc(1024);
    int* colv     = (int*)alloc((size_t)E * 4);
    int* rank_    = (int*)alloc((size_t)E * 4);
    int* srcv     = (int*)alloc((size_t)E * 4);
    int* dstv     = (int*)alloc((size_t)E * 4);
    int* flag     = (int*)alloc(256);

    int NB = (N + 255) / 256;          // <= 256 required for single-block scan2
    int blocksN4 = (N + 3) / 4;
    int rowTiles = (N + 63) / 64;
    int blocksE4 = (E + 1023) / 1024;  // 4 edges per thread

    int nchk = 2 * E < 512 ? 2 * E : 512;
    k_prep<<<NB + 7, 256, 0, stream>>>(counts, N, ei, nchk, flag, W1, Wt1, W2, Wt2, NB);
    k_rank<<<blocksE4, 256, 0, stream>>>(ei, flag, counts, rank_, srcv, dstv, E);
    k_scan1<<<NB, 256, 0, stream>>>(counts, incl, bsums, N);
    k_scan2<<<1, 256, 0, stream>>>(bsums, NB);
    k_scan3<<<NB, 256, 0, stream>>>(incl, bsums, rowptr, N);
    k_place<<<blocksE4, 256, 0, stream>>>(rank_, srcv, dstv, rowptr, colv, E);

    // layer 1: Fh = 128 (A = x f32, converted in-register); alpha fused
    k_gemm_mfma<128, true><<<rowTiles, 256, 0, stream>>>(x, Wt1, a1s, a1d, h, as_, ad_, N);
    k_agg<128, true, true><<<blocksN4, 256, 0, stream>>>(rowptr, colv, as_, ad_,
                                                         (const unsigned*)h, b1, out1b, N);

    // layer 2: Fout = 64 (A = out1b bf16); alpha fused
    k_gemm_mfma<64, false><<<rowTiles, 256, 0, stream>>>(out1b, Wt2, a2s, a2d, h, as_, ad_, N);
    k_agg<64, false, false><<<blocksN4, 256, 0, stream>>>(rowptr, colv, as_, ad_,
                                                          (const unsigned*)h, b2, out, N);
}